// Round 1
// baseline (1394.213 us; speedup 1.0000x reference)
//
#include <hip/hip_runtime.h>
#include <math.h>

#define K_CODES 1024
#define D_DIM   64
#define N_PTS   65536
#define HW      4096
#define BSTRIDE 262144   // 64*4096 elements per batch image

// output offsets (floats)
#define OFF_EQ    0
#define OFF_IDX   4194304
#define OFF_LOSS  4259840
#define OFF_STATS 4259841
#define OFF_EMB   4259843
#define OFF_CSB   4325379
#define OFF_EAB   4326403

// workspace layout (float slots)
#define WS_LOSS 0
#define WS_NVAL 1
#define WS_SCS  2
#define WS_CNT  4
#define WS_ESQ  (4 + 1024)
#define WS_ESUM (4 + 2048)
#define WS_RAND (WS_ESUM + 65536)

// ---------------- threefry2x32 (JAX-compatible) ----------------
__device__ __forceinline__ void tf_block(unsigned k0, unsigned k1,
                                         unsigned& x0, unsigned& x1) {
  unsigned ks2 = k0 ^ k1 ^ 0x1BD11BDAu;
  x0 += k0; x1 += k1;
#define RR(r) { x0 += x1; x1 = (x1 << r) | (x1 >> (32 - r)); x1 ^= x0; }
  RR(13) RR(15) RR(26) RR(6)
  x0 += k1; x1 += ks2 + 1u;
  RR(17) RR(29) RR(16) RR(24)
  x0 += ks2; x1 += k0 + 2u;
  RR(13) RR(15) RR(26) RR(6)
  x0 += k0; x1 += k1 + 3u;
  RR(17) RR(29) RR(16) RR(24)
  x0 += k1; x1 += ks2 + 4u;
  RR(13) RR(15) RR(26) RR(6)
  x0 += ks2; x1 += k0 + 5u;
#undef RR
}

// bits[c] of jax random_bits(k2, 32, (1024,)) where k2 = split(key(1))[1]
__device__ __forceinline__ unsigned tf_rand_bits(int c) {
  // split(key(1)): threefry((0,1), iota(4)) -> pairs (0,2),(1,3); k2 = (y1_a, y1_b)
  unsigned a0 = 0u, a1 = 2u; tf_block(0u, 1u, a0, a1);
  unsigned b0 = 1u, b1 = 3u; tf_block(0u, 1u, b0, b1);
  unsigned K0 = a1, K1 = b1;
  unsigned x0, x1;
  if (c < 512) { x0 = (unsigned)c; x1 = (unsigned)(512 + c); tf_block(K0, K1, x0, x1); return x0; }
  else         { x0 = (unsigned)(c - 512); x1 = (unsigned)c; tf_block(K0, K1, x0, x1); return x1; }
}

// ---------------- K0: codebook squared norms ----------------
__global__ void k_esq(const float* __restrict__ E, float* __restrict__ esq) {
  int c = blockIdx.x * blockDim.x + threadIdx.x;
  if (c >= K_CODES) return;
  const float4* e4 = reinterpret_cast<const float4*>(E + c * D_DIM);
  float s = 0.f;
#pragma unroll
  for (int j = 0; j < 16; ++j) {
    float4 v = e4[j];
    s += v.x * v.x + v.y * v.y + v.z * v.z + v.w * v.w;
  }
  esq[c] = s;
}

// ---------------- K1: distances + argmin + scatter ----------------
#define CHUNK 128
__global__ __launch_bounds__(256) void k_assign(
    const float* __restrict__ Z, const float* __restrict__ E,
    const float* __restrict__ esq,
    float* __restrict__ eq_out, float* __restrict__ idx_out,
    float* __restrict__ counts, float* __restrict__ esum,
    float* __restrict__ loss_acc) {
  __shared__ float sE[CHUNK * D_DIM];
  __shared__ float sQ[CHUNK];
  int n = blockIdx.x * 256 + threadIdx.x;
  int zbase = (n >> 12) * BSTRIDE + (n & 4095);

  float zr[64];
#pragma unroll
  for (int d = 0; d < 64; ++d) zr[d] = Z[zbase + d * HW];
  float zsq = 0.f;
#pragma unroll
  for (int d = 0; d < 64; ++d) zsq = fmaf(zr[d], zr[d], zsq);

  float best1 = 3.4e38f, best2 = 3.4e38f;
  int bi = 0;
  for (int ch = 0; ch < K_CODES / CHUNK; ++ch) {
    __syncthreads();
    const float4* src = reinterpret_cast<const float4*>(E + ch * CHUNK * D_DIM);
    float4* dst = reinterpret_cast<float4*>(sE);
#pragma unroll
    for (int j = 0; j < 8; ++j) dst[threadIdx.x + 256 * j] = src[threadIdx.x + 256 * j];
    if (threadIdx.x < CHUNK) sQ[threadIdx.x] = esq[ch * CHUNK + threadIdx.x];
    __syncthreads();

    for (int c = 0; c < CHUNK; ++c) {
      const float4* ep = reinterpret_cast<const float4*>(sE + c * D_DIM);
      float d0 = 0.f, d1 = 0.f, d2 = 0.f, d3 = 0.f;
#pragma unroll
      for (int j = 0; j < 16; ++j) {
        float4 v = ep[j];
        d0 = fmaf(zr[4 * j + 0], v.x, d0);
        d1 = fmaf(zr[4 * j + 1], v.y, d1);
        d2 = fmaf(zr[4 * j + 2], v.z, d2);
        d3 = fmaf(zr[4 * j + 3], v.w, d3);
      }
      float dot = (d0 + d1) + (d2 + d3);
      float dist = zsq + sQ[c] - 2.f * dot;
      int cg = ch * CHUNK + c;
      bool better = dist < best1;
      best2 = better ? best1 : fminf(best2, dist);
      best1 = better ? dist : best1;
      bi = better ? cg : bi;
    }
  }

  // near-tie: exact float64 re-score so argmin matches an f64 reference
  if (best2 - best1 < 0.01f) {
    double zsqd = 0.0;
#pragma unroll
    for (int d = 0; d < 64; ++d) zsqd += (double)zr[d] * (double)zr[d];
    double b1 = 1e300; int bid = 0;
    for (int c = 0; c < K_CODES; ++c) {
      const float* ep = E + c * D_DIM;
      double dot = 0.0, es = 0.0;
      for (int d = 0; d < 64; ++d) {
        double ev = (double)ep[d];
        dot += (double)zr[d] * ev;
        es  += ev * ev;
      }
      double dist = zsqd + es - 2.0 * dot;
      if (dist < b1) { b1 = dist; bid = c; }
    }
    bi = bid;
  }

  idx_out[n] = (float)bi;
  atomicAdd(&counts[bi], 1.0f);

  const float4* er = reinterpret_cast<const float4*>(E + bi * D_DIM);
  float lsum = 0.f;
#pragma unroll
  for (int j = 0; j < 16; ++j) {
    float4 ev = er[j];
    int d = 4 * j;
    eq_out[zbase + (d + 0) * HW] = ev.x;
    eq_out[zbase + (d + 1) * HW] = ev.y;
    eq_out[zbase + (d + 2) * HW] = ev.z;
    eq_out[zbase + (d + 3) * HW] = ev.w;
    float f0 = ev.x - zr[d + 0], f1 = ev.y - zr[d + 1];
    float f2 = ev.z - zr[d + 2], f3 = ev.w - zr[d + 3];
    lsum = fmaf(f0, f0, lsum); lsum = fmaf(f1, f1, lsum);
    lsum = fmaf(f2, f2, lsum); lsum = fmaf(f3, f3, lsum);
    atomicAdd(&esum[bi * D_DIM + d + 0], zr[d + 0]);
    atomicAdd(&esum[bi * D_DIM + d + 1], zr[d + 1]);
    atomicAdd(&esum[bi * D_DIM + d + 2], zr[d + 2]);
    atomicAdd(&esum[bi * D_DIM + d + 3], zr[d + 3]);
  }
#pragma unroll
  for (int off = 32; off >= 1; off >>= 1) lsum += __shfl_xor(lsum, off, 64);
  if ((threadIdx.x & 63) == 0) atomicAdd(loss_acc, lsum);
}

// ---------------- K2: stats, smoothing scalars, threefry ----------------
__global__ __launch_bounds__(1024) void k_stats(
    const float* __restrict__ counts, const float* __restrict__ cluster_size,
    float* __restrict__ out, float* __restrict__ ws,
    unsigned* __restrict__ rnd, const float* __restrict__ loss_acc) {
  __shared__ float red[16][4];
  int c = threadIdx.x;
  float cnt = counts[c];
  float csb = cluster_size[c] * 0.99f + cnt * 0.01f;
  out[OFF_CSB + c] = csb;

  float v_n = csb;
  float v_s = csb + 1e-5f;
  float p = cnt * (1.0f / 65536.0f);
  float v_p = p * logf(p + 1e-10f);
  float v_u = cnt > 0.f ? 1.f : 0.f;
#pragma unroll
  for (int off = 32; off >= 1; off >>= 1) {
    v_n += __shfl_xor(v_n, off, 64);
    v_s += __shfl_xor(v_s, off, 64);
    v_p += __shfl_xor(v_p, off, 64);
    v_u += __shfl_xor(v_u, off, 64);
  }
  int lane = threadIdx.x & 63, wid = threadIdx.x >> 6;
  if (lane == 0) { red[wid][0] = v_n; red[wid][1] = v_s; red[wid][2] = v_p; red[wid][3] = v_u; }
  __syncthreads();
  if (threadIdx.x == 0) {
    float nsum = 0.f, ssum = 0.f, psum = 0.f, usum = 0.f;
    for (int w = 0; w < 16; ++w) {
      nsum += red[w][0]; ssum += red[w][1]; psum += red[w][2]; usum += red[w][3];
    }
    ws[WS_NVAL] = nsum;
    ws[WS_SCS]  = ssum;
    out[OFF_STATS + 0] = expf(-psum);
    out[OFF_STATS + 1] = usum;
    out[OFF_LOSS] = 1.25f * loss_acc[0] * (1.0f / 4194304.0f);
  }
  rnd[c] = tf_rand_bits(c) & 0xFFFFu;  // randint(key(1),(K,),0,65536)
}

// ---------------- K3: EMA buffers + embedding update ----------------
__global__ __launch_bounds__(64) void k_update(
    const float* __restrict__ Z, const float* __restrict__ embed_avg,
    const float* __restrict__ esum, const float* __restrict__ ws,
    const unsigned* __restrict__ rnd, float* __restrict__ out) {
  int c = blockIdx.x, d = threadIdx.x;
  float csb = out[OFF_CSB + c];
  float nval = ws[WS_NVAL], scs = ws[WS_SCS];
  float cs = (csb + 1e-5f) / fmaxf(scs, 1e-8f) * nval;
  bool dead = cs < 1.0f;
  float csf = dead ? 1.0f : cs;
  float ea_ema = embed_avg[c * D_DIM + d] * 0.99f + esum[c * D_DIM + d] * 0.01f;
  int r = (int)rnd[c];
  float zv = Z[(r >> 12) * BSTRIDE + d * HW + (r & 4095)];
  float ea = dead ? zv : ea_ema;
  out[OFF_EAB + c * D_DIM + d] = ea;
  out[OFF_EMB + c * D_DIM + d] = ea / csf;
}

extern "C" void kernel_launch(void* const* d_in, const int* in_sizes, int n_in,
                              void* d_out, int out_size, void* d_ws, size_t ws_size,
                              hipStream_t stream) {
  const float* Z  = (const float*)d_in[0];
  const float* E  = (const float*)d_in[1];
  const float* CS = (const float*)d_in[2];
  const float* EA = (const float*)d_in[3];
  float* out = (float*)d_out;
  float* ws  = (float*)d_ws;
  unsigned* rnd = (unsigned*)(ws + WS_RAND);

  hipMemsetAsync(ws, 0, (size_t)(WS_ESUM + 65536) * sizeof(float), stream);
  k_esq<<<4, 256, 0, stream>>>(E, ws + WS_ESQ);
  k_assign<<<N_PTS / 256, 256, 0, stream>>>(Z, E, ws + WS_ESQ,
                                            out + OFF_EQ, out + OFF_IDX,
                                            ws + WS_CNT, ws + WS_ESUM, ws + WS_LOSS);
  k_stats<<<1, 1024, 0, stream>>>(ws + WS_CNT, CS, out, ws, rnd, ws + WS_LOSS);
  k_update<<<K_CODES, 64, 0, stream>>>(Z, EA, ws + WS_ESUM, ws, rnd, out);
}

// Round 2
// 397.090 us; speedup vs baseline: 3.5111x; 3.5111x over previous
//
#include <hip/hip_runtime.h>
#include <math.h>

#define K_CODES 1024
#define D_DIM   64
#define N_PTS   65536
#define HW      4096
#define BSTRIDE 262144   // 64*4096 elements per batch image
#define KSPLIT  4
#define CODES_PER (K_CODES / KSPLIT)   // 256
#define CHUNK   128
#define KSN     (KSPLIT * N_PTS)       // 262144

// output offsets (floats)
#define OFF_EQ    0
#define OFF_IDX   4194304
#define OFF_LOSS  4259840
#define OFF_STATS 4259841
#define OFF_EMB   4259843
#define OFF_CSB   4325379
#define OFF_EAB   4326403

// workspace layout (float slots)
#define WS_LOSS 0
#define WS_NVAL 1
#define WS_SCS  2
#define WS_CNT  4
#define WS_ESQ  1028
#define WS_RAND 2052
#define WS_PART 3076
// partial arrays: PB1 @ +0, PI1 @ +KSN, PB2 @ +2*KSN, PI2 @ +3*KSN, PB3 @ +4*KSN

#define M_RESCORE 0.01f
#define M_FULL    5e-4f

// ---------------- threefry2x32 (JAX-compatible) ----------------
__device__ __forceinline__ void tf_block(unsigned k0, unsigned k1,
                                         unsigned& x0, unsigned& x1) {
  unsigned ks2 = k0 ^ k1 ^ 0x1BD11BDAu;
  x0 += k0; x1 += k1;
#define RR(r) { x0 += x1; x1 = (x1 << r) | (x1 >> (32 - r)); x1 ^= x0; }
  RR(13) RR(15) RR(26) RR(6)
  x0 += k1; x1 += ks2 + 1u;
  RR(17) RR(29) RR(16) RR(24)
  x0 += ks2; x1 += k0 + 2u;
  RR(13) RR(15) RR(26) RR(6)
  x0 += k0; x1 += k1 + 3u;
  RR(17) RR(29) RR(16) RR(24)
  x0 += k1; x1 += ks2 + 4u;
  RR(13) RR(15) RR(26) RR(6)
  x0 += ks2; x1 += k0 + 5u;
#undef RR
}

__device__ __forceinline__ unsigned tf_rand_bits(int c) {
  unsigned a0 = 0u, a1 = 2u; tf_block(0u, 1u, a0, a1);
  unsigned b0 = 1u, b1 = 3u; tf_block(0u, 1u, b0, b1);
  unsigned K0 = a1, K1 = b1;
  unsigned x0, x1;
  if (c < 512) { x0 = (unsigned)c; x1 = (unsigned)(512 + c); tf_block(K0, K1, x0, x1); return x0; }
  else         { x0 = (unsigned)(c - 512); x1 = (unsigned)c; tf_block(K0, K1, x0, x1); return x1; }
}

// ---------------- K0: codebook squared norms ----------------
__global__ void k_esq(const float* __restrict__ E, float* __restrict__ esq) {
  int c = blockIdx.x * blockDim.x + threadIdx.x;
  if (c >= K_CODES) return;
  const float4* e4 = reinterpret_cast<const float4*>(E + c * D_DIM);
  float s = 0.f;
#pragma unroll
  for (int j = 0; j < 16; ++j) {
    float4 v = e4[j];
    s += v.x * v.x + v.y * v.y + v.z * v.z + v.w * v.w;
  }
  esq[c] = s;
}

// ---------------- K1: K-split distances, top-3 partials ----------------
__global__ __launch_bounds__(256, 4) void k_assign(
    const float* __restrict__ Z, const float* __restrict__ E,
    const float* __restrict__ esq, float* __restrict__ part) {
  __shared__ float sE[CHUNK * D_DIM];
  __shared__ float sQ[CHUNK];
  const int split = blockIdx.x & (KSPLIT - 1);
  const int n = (blockIdx.x >> 2) * 256 + threadIdx.x;
  const int zbase = (n >> 12) * BSTRIDE + (n & 4095);

  float zr[64];
#pragma unroll
  for (int d = 0; d < 64; ++d) zr[d] = Z[zbase + d * HW];
  float zsq = 0.f;
#pragma unroll
  for (int d = 0; d < 64; ++d) zsq = fmaf(zr[d], zr[d], zsq);

  float b1 = 3.4e38f, b2 = 3.4e38f, b3 = 3.4e38f;
  int i1 = 0, i2 = 0;
  const int c00 = split * CODES_PER;

  for (int ch = 0; ch < CODES_PER / CHUNK; ++ch) {
    const int cbase = c00 + ch * CHUNK;
    __syncthreads();
    // async global -> LDS staging, 16B per lane per issue (linear layout)
#pragma unroll
    for (int j = 0; j < 8; ++j) {
      const float* gsrc = E + cbase * D_DIM + j * 1024 + threadIdx.x * 4;
      float* ldst = sE + j * 1024 + threadIdx.x * 4;
      __builtin_amdgcn_global_load_lds(
          (const __attribute__((address_space(1))) float*)gsrc,
          (__attribute__((address_space(3))) float*)ldst, 16, 0, 0);
    }
    if (threadIdx.x < CHUNK) sQ[threadIdx.x] = esq[cbase + threadIdx.x];
    __syncthreads();

    for (int c = 0; c < CHUNK; ++c) {
      const float4* ep = reinterpret_cast<const float4*>(sE + c * D_DIM);
      float d0 = 0.f, d1 = 0.f, d2 = 0.f, d3 = 0.f;
#pragma unroll
      for (int j = 0; j < 16; ++j) {
        float4 v = ep[j];
        d0 = fmaf(zr[4 * j + 0], v.x, d0);
        d1 = fmaf(zr[4 * j + 1], v.y, d1);
        d2 = fmaf(zr[4 * j + 2], v.z, d2);
        d3 = fmaf(zr[4 * j + 3], v.w, d3);
      }
      float dist = zsq + sQ[c] - 2.f * ((d0 + d1) + (d2 + d3));
      int cg = cbase + c;
      bool lt1 = dist < b1, lt2 = dist < b2, lt3 = dist < b3;
      b3 = lt2 ? b2 : (lt3 ? dist : b3);
      b2 = lt1 ? b1 : (lt2 ? dist : b2);
      i2 = lt1 ? i1 : (lt2 ? cg : i2);
      b1 = lt1 ? dist : b1;
      i1 = lt1 ? cg : i1;
    }
  }
  const int o = split * N_PTS + n;
  part[o]           = b1;
  part[KSN + o]     = (float)i1;
  part[2 * KSN + o] = b2;
  part[3 * KSN + o] = (float)i2;
  part[4 * KSN + o] = b3;
}

// ---------------- K2: merge partials, tie-resolve, gather/eq/loss ----------------
__global__ __launch_bounds__(256) void k_combine(
    const float* __restrict__ Z, const float* __restrict__ E,
    const float* __restrict__ part,
    float* __restrict__ eq_out, float* __restrict__ idx_out,
    float* __restrict__ counts, float* __restrict__ loss_acc) {
  __shared__ float lred[4];
  const int n = blockIdx.x * 256 + threadIdx.x;
  const int zbase = (n >> 12) * BSTRIDE + (n & 4095);

  float dd[12], ii[12];
#pragma unroll
  for (int s = 0; s < KSPLIT; ++s) {
    int o = s * N_PTS + n;
    dd[3 * s + 0] = part[o];            ii[3 * s + 0] = part[KSN + o];
    dd[3 * s + 1] = part[2 * KSN + o];  ii[3 * s + 1] = part[3 * KSN + o];
    dd[3 * s + 2] = part[4 * KSN + o];  ii[3 * s + 2] = -1.f;
  }
  float w1 = 3.4e38f, w2 = 3.4e38f, w3 = 3.4e38f;
  int j1 = -1, j2 = -1, i1g = 0, i2g = 0;
#pragma unroll
  for (int j = 0; j < 12; ++j) if (dd[j] < w1) { w1 = dd[j]; i1g = (int)ii[j]; j1 = j; }
#pragma unroll
  for (int j = 0; j < 12; ++j) if (j != j1 && dd[j] < w2) { w2 = dd[j]; i2g = (int)ii[j]; j2 = j; }
#pragma unroll
  for (int j = 0; j < 12; ++j) if (j != j1 && j != j2 && dd[j] < w3) w3 = dd[j];
  if (i2g < 0) i2g = i1g;  // safety (b3 can't be global-2nd, see merge argument)

  float zr[64];
#pragma unroll
  for (int d = 0; d < 64; ++d) zr[d] = Z[zbase + d * HW];

  int bi = i1g;
  if (w3 - w1 < M_FULL) {
    // ultra-rare: 3-way near-tie -> exact f64 full scan
    double b = 1e300; int bb = 0;
    for (int c = 0; c < K_CODES; ++c) {
      const float* ep = E + c * D_DIM;
      double s = 0.0;
      for (int d = 0; d < 64; ++d) {
        double v = (double)zr[d] - (double)ep[d];
        s += v * v;
      }
      if (s < b) { b = s; bb = c; }
    }
    bi = bb;
  } else if (w2 - w1 < M_RESCORE) {
    // near-tie: exact f64 rescore of the two candidates
    const float* ea = E + i1g * D_DIM;
    const float* eb = E + i2g * D_DIM;
    double da = 0.0, db = 0.0;
#pragma unroll
    for (int d = 0; d < 64; ++d) {
      double va = (double)zr[d] - (double)ea[d]; da += va * va;
      double vb = (double)zr[d] - (double)eb[d]; db += vb * vb;
    }
    if (db < da || (db == da && i2g < i1g)) bi = i2g;
  }

  idx_out[n] = (float)bi;
  atomicAdd(&counts[bi], 1.0f);

  const float4* er = reinterpret_cast<const float4*>(E + bi * D_DIM);
  float lsum = 0.f;
#pragma unroll
  for (int j = 0; j < 16; ++j) {
    float4 ev = er[j];
    int d = 4 * j;
    eq_out[zbase + (d + 0) * HW] = ev.x;
    eq_out[zbase + (d + 1) * HW] = ev.y;
    eq_out[zbase + (d + 2) * HW] = ev.z;
    eq_out[zbase + (d + 3) * HW] = ev.w;
    float f0 = ev.x - zr[d + 0], f1 = ev.y - zr[d + 1];
    float f2 = ev.z - zr[d + 2], f3 = ev.w - zr[d + 3];
    lsum = fmaf(f0, f0, lsum); lsum = fmaf(f1, f1, lsum);
    lsum = fmaf(f2, f2, lsum); lsum = fmaf(f3, f3, lsum);
  }
#pragma unroll
  for (int off = 32; off >= 1; off >>= 1) lsum += __shfl_xor(lsum, off, 64);
  int lane = threadIdx.x & 63, wid = threadIdx.x >> 6;
  if (lane == 0) lred[wid] = lsum;
  __syncthreads();
  if (threadIdx.x == 0)
    atomicAdd(loss_acc, lred[0] + lred[1] + lred[2] + lred[3]);
}

// ---------------- fallback: single-pass assign (if ws too small) ----------------
__global__ __launch_bounds__(256) void k_solo(
    const float* __restrict__ Z, const float* __restrict__ E,
    const float* __restrict__ esq,
    float* __restrict__ eq_out, float* __restrict__ idx_out,
    float* __restrict__ counts, float* __restrict__ loss_acc) {
  __shared__ float sE[CHUNK * D_DIM];
  __shared__ float sQ[CHUNK];
  int n = blockIdx.x * 256 + threadIdx.x;
  int zbase = (n >> 12) * BSTRIDE + (n & 4095);

  float zr[64];
#pragma unroll
  for (int d = 0; d < 64; ++d) zr[d] = Z[zbase + d * HW];
  float zsq = 0.f;
#pragma unroll
  for (int d = 0; d < 64; ++d) zsq = fmaf(zr[d], zr[d], zsq);

  float b1 = 3.4e38f, b2 = 3.4e38f, b3 = 3.4e38f;
  int i1 = 0, i2 = 0;
  for (int ch = 0; ch < K_CODES / CHUNK; ++ch) {
    __syncthreads();
    const float4* src = reinterpret_cast<const float4*>(E + ch * CHUNK * D_DIM);
    float4* dst = reinterpret_cast<float4*>(sE);
#pragma unroll
    for (int j = 0; j < 8; ++j) dst[threadIdx.x + 256 * j] = src[threadIdx.x + 256 * j];
    if (threadIdx.x < CHUNK) sQ[threadIdx.x] = esq[ch * CHUNK + threadIdx.x];
    __syncthreads();
    for (int c = 0; c < CHUNK; ++c) {
      const float4* ep = reinterpret_cast<const float4*>(sE + c * D_DIM);
      float d0 = 0.f, d1 = 0.f, d2 = 0.f, d3 = 0.f;
#pragma unroll
      for (int j = 0; j < 16; ++j) {
        float4 v = ep[j];
        d0 = fmaf(zr[4 * j + 0], v.x, d0);
        d1 = fmaf(zr[4 * j + 1], v.y, d1);
        d2 = fmaf(zr[4 * j + 2], v.z, d2);
        d3 = fmaf(zr[4 * j + 3], v.w, d3);
      }
      float dist = zsq + sQ[c] - 2.f * ((d0 + d1) + (d2 + d3));
      int cg = ch * CHUNK + c;
      bool lt1 = dist < b1, lt2 = dist < b2, lt3 = dist < b3;
      b3 = lt2 ? b2 : (lt3 ? dist : b3);
      b2 = lt1 ? b1 : (lt2 ? dist : b2);
      i2 = lt1 ? i1 : (lt2 ? cg : i2);
      b1 = lt1 ? dist : b1;
      i1 = lt1 ? cg : i1;
    }
  }
  int bi = i1;
  if (b3 - b1 < M_FULL) {
    double b = 1e300; int bb = 0;
    for (int c = 0; c < K_CODES; ++c) {
      const float* ep = E + c * D_DIM;
      double s = 0.0;
      for (int d = 0; d < 64; ++d) { double v = (double)zr[d] - (double)ep[d]; s += v * v; }
      if (s < b) { b = s; bb = c; }
    }
    bi = bb;
  } else if (b2 - b1 < M_RESCORE) {
    const float* ea = E + i1 * D_DIM;
    const float* eb = E + i2 * D_DIM;
    double da = 0.0, db = 0.0;
#pragma unroll
    for (int d = 0; d < 64; ++d) {
      double va = (double)zr[d] - (double)ea[d]; da += va * va;
      double vb = (double)zr[d] - (double)eb[d]; db += vb * vb;
    }
    if (db < da || (db == da && i2 < i1)) bi = i2;
  }

  idx_out[n] = (float)bi;
  atomicAdd(&counts[bi], 1.0f);
  const float4* er = reinterpret_cast<const float4*>(E + bi * D_DIM);
  float lsum = 0.f;
#pragma unroll
  for (int j = 0; j < 16; ++j) {
    float4 ev = er[j];
    int d = 4 * j;
    eq_out[zbase + (d + 0) * HW] = ev.x;
    eq_out[zbase + (d + 1) * HW] = ev.y;
    eq_out[zbase + (d + 2) * HW] = ev.z;
    eq_out[zbase + (d + 3) * HW] = ev.w;
    float f0 = ev.x - zr[d + 0], f1 = ev.y - zr[d + 1];
    float f2 = ev.z - zr[d + 2], f3 = ev.w - zr[d + 3];
    lsum = fmaf(f0, f0, lsum); lsum = fmaf(f1, f1, lsum);
    lsum = fmaf(f2, f2, lsum); lsum = fmaf(f3, f3, lsum);
  }
#pragma unroll
  for (int off = 32; off >= 1; off >>= 1) lsum += __shfl_xor(lsum, off, 64);
  if ((threadIdx.x & 63) == 0) atomicAdd(loss_acc, lsum);
}

// ---------------- K3: stats, smoothing scalars, threefry ----------------
__global__ __launch_bounds__(1024) void k_stats(
    const float* __restrict__ counts, const float* __restrict__ cluster_size,
    float* __restrict__ out, float* __restrict__ ws,
    unsigned* __restrict__ rnd, const float* __restrict__ loss_acc) {
  __shared__ float red[16][4];
  int c = threadIdx.x;
  float cnt = counts[c];
  float csb = cluster_size[c] * 0.99f + cnt * 0.01f;
  out[OFF_CSB + c] = csb;

  float v_n = csb;
  float v_s = csb + 1e-5f;
  float p = cnt * (1.0f / 65536.0f);
  float v_p = p * logf(p + 1e-10f);
  float v_u = cnt > 0.f ? 1.f : 0.f;
#pragma unroll
  for (int off = 32; off >= 1; off >>= 1) {
    v_n += __shfl_xor(v_n, off, 64);
    v_s += __shfl_xor(v_s, off, 64);
    v_p += __shfl_xor(v_p, off, 64);
    v_u += __shfl_xor(v_u, off, 64);
  }
  int lane = threadIdx.x & 63, wid = threadIdx.x >> 6;
  if (lane == 0) { red[wid][0] = v_n; red[wid][1] = v_s; red[wid][2] = v_p; red[wid][3] = v_u; }
  __syncthreads();
  if (threadIdx.x == 0) {
    float nsum = 0.f, ssum = 0.f, psum = 0.f, usum = 0.f;
    for (int w = 0; w < 16; ++w) {
      nsum += red[w][0]; ssum += red[w][1]; psum += red[w][2]; usum += red[w][3];
    }
    ws[WS_NVAL] = nsum;
    ws[WS_SCS]  = ssum;
    out[OFF_STATS + 0] = expf(-psum);
    out[OFF_STATS + 1] = usum;
    out[OFF_LOSS] = 1.25f * loss_acc[0] * (1.0f / 4194304.0f);
  }
  rnd[c] = tf_rand_bits(c) & 0xFFFFu;
}

// ---------------- K4: embed_sum scan + EMA buffers + embedding ----------------
__global__ __launch_bounds__(64) void k_update(
    const float* __restrict__ Z, const float* __restrict__ embed_avg,
    const float* __restrict__ ws, const unsigned* __restrict__ rnd,
    const float* __restrict__ idxf, float* __restrict__ out) {
  const int c = blockIdx.x, d = threadIdx.x;
  const float cf = (float)c;
  float es = 0.f;
  const float4* i4 = reinterpret_cast<const float4*>(idxf);
  float4 cur = i4[d];
  for (int it = 0; it < 256; ++it) {
    float4 nxt = cur;
    if (it < 255) nxt = i4[(it + 1) * 64 + d];
    unsigned long long m0 = __ballot(cur.x == cf);
    unsigned long long m1 = __ballot(cur.y == cf);
    unsigned long long m2 = __ballot(cur.z == cf);
    unsigned long long m3 = __ballot(cur.w == cf);
    while (m0) { int b = __ffsll((unsigned long long)m0) - 1; m0 &= m0 - 1;
      int p = it * 256 + b * 4 + 0; es += Z[(p >> 12) * BSTRIDE + d * HW + (p & 4095)]; }
    while (m1) { int b = __ffsll((unsigned long long)m1) - 1; m1 &= m1 - 1;
      int p = it * 256 + b * 4 + 1; es += Z[(p >> 12) * BSTRIDE + d * HW + (p & 4095)]; }
    while (m2) { int b = __ffsll((unsigned long long)m2) - 1; m2 &= m2 - 1;
      int p = it * 256 + b * 4 + 2; es += Z[(p >> 12) * BSTRIDE + d * HW + (p & 4095)]; }
    while (m3) { int b = __ffsll((unsigned long long)m3) - 1; m3 &= m3 - 1;
      int p = it * 256 + b * 4 + 3; es += Z[(p >> 12) * BSTRIDE + d * HW + (p & 4095)]; }
    cur = nxt;
  }
  float csb = out[OFF_CSB + c];
  float nval = ws[WS_NVAL], scs = ws[WS_SCS];
  float cs = (csb + 1e-5f) / fmaxf(scs, 1e-8f) * nval;
  bool dead = cs < 1.0f;
  float csf = dead ? 1.0f : cs;
  float ea_ema = embed_avg[c * D_DIM + d] * 0.99f + es * 0.01f;
  int r = (int)rnd[c];
  float zv = Z[(r >> 12) * BSTRIDE + d * HW + (r & 4095)];
  float ea = dead ? zv : ea_ema;
  out[OFF_EAB + c * D_DIM + d] = ea;
  out[OFF_EMB + c * D_DIM + d] = ea / csf;
}

extern "C" void kernel_launch(void* const* d_in, const int* in_sizes, int n_in,
                              void* d_out, int out_size, void* d_ws, size_t ws_size,
                              hipStream_t stream) {
  const float* Z  = (const float*)d_in[0];
  const float* E  = (const float*)d_in[1];
  const float* CS = (const float*)d_in[2];
  const float* EA = (const float*)d_in[3];
  float* out = (float*)d_out;
  float* ws  = (float*)d_ws;
  unsigned* rnd = (unsigned*)(ws + WS_RAND);

  const size_t need = (size_t)(WS_PART + 5 * KSN + 16) * sizeof(float);
  const bool big = ws_size >= need;

  hipMemsetAsync(ws, 0, 1028 * sizeof(float), stream);
  k_esq<<<4, 256, 0, stream>>>(E, ws + WS_ESQ);
  if (big) {
    k_assign<<<N_PTS / 256 * KSPLIT, 256, 0, stream>>>(Z, E, ws + WS_ESQ, ws + WS_PART);
    k_combine<<<N_PTS / 256, 256, 0, stream>>>(Z, E, ws + WS_PART,
                                               out + OFF_EQ, out + OFF_IDX,
                                               ws + WS_CNT, ws + WS_LOSS);
  } else {
    k_solo<<<N_PTS / 256, 256, 0, stream>>>(Z, E, ws + WS_ESQ,
                                            out + OFF_EQ, out + OFF_IDX,
                                            ws + WS_CNT, ws + WS_LOSS);
  }
  k_stats<<<1, 1024, 0, stream>>>(ws + WS_CNT, CS, out, ws, rnd, ws + WS_LOSS);
  k_update<<<K_CODES, 64, 0, stream>>>(Z, EA, ws, rnd, out + OFF_IDX, out);
}

// Round 3
// 258.573 us; speedup vs baseline: 5.3919x; 1.5357x over previous
//
#include <hip/hip_runtime.h>
#include <math.h>

#define K_CODES 1024
#define D_DIM   64
#define N_PTS   65536
#define HW      4096
#define BSTRIDE 262144   // 64*4096 elements per batch image
#define KSPLIT  4
#define CODES_PER (K_CODES / KSPLIT)   // 256
#define CHUNK   128
#define KSN     (KSPLIT * N_PTS)       // 262144

// output offsets (floats)
#define OFF_EQ    0
#define OFF_IDX   4194304
#define OFF_LOSS  4259840
#define OFF_STATS 4259841
#define OFF_EMB   4259843
#define OFF_CSB   4325379
#define OFF_EAB   4326403

// workspace layout (float slots)
#define WS_LOSS 0
#define WS_NVAL 1
#define WS_SCS  2
#define WS_CNT  4
#define WS_ESQ  1028
#define WS_RAND 2052
#define WS_PART 3076
// partial arrays: PB1 @ +0, PI1 @ +KSN, PB2 @ +2*KSN, PI2 @ +3*KSN, PB3 @ +4*KSN
#define WS_ZT   (WS_PART + 5 * KSN)    // transposed z: [N][64]

#define M_RESCORE 0.01f
#define M_FULL    5e-4f

// ---------------- threefry2x32 (JAX-compatible) ----------------
__device__ __forceinline__ void tf_block(unsigned k0, unsigned k1,
                                         unsigned& x0, unsigned& x1) {
  unsigned ks2 = k0 ^ k1 ^ 0x1BD11BDAu;
  x0 += k0; x1 += k1;
#define RR(r) { x0 += x1; x1 = (x1 << r) | (x1 >> (32 - r)); x1 ^= x0; }
  RR(13) RR(15) RR(26) RR(6)
  x0 += k1; x1 += ks2 + 1u;
  RR(17) RR(29) RR(16) RR(24)
  x0 += ks2; x1 += k0 + 2u;
  RR(13) RR(15) RR(26) RR(6)
  x0 += k0; x1 += k1 + 3u;
  RR(17) RR(29) RR(16) RR(24)
  x0 += k1; x1 += ks2 + 4u;
  RR(13) RR(15) RR(26) RR(6)
  x0 += ks2; x1 += k0 + 5u;
#undef RR
}

__device__ __forceinline__ unsigned tf_rand_bits(int c) {
  unsigned a0 = 0u, a1 = 2u; tf_block(0u, 1u, a0, a1);
  unsigned b0 = 1u, b1 = 3u; tf_block(0u, 1u, b0, b1);
  unsigned K0 = a1, K1 = b1;
  unsigned x0, x1;
  if (c < 512) { x0 = (unsigned)c; x1 = (unsigned)(512 + c); tf_block(K0, K1, x0, x1); return x0; }
  else         { x0 = (unsigned)(c - 512); x1 = (unsigned)c; tf_block(K0, K1, x0, x1); return x1; }
}

// ---------------- K0: codebook squared norms ----------------
__global__ void k_esq(const float* __restrict__ E, float* __restrict__ esq) {
  int c = blockIdx.x * blockDim.x + threadIdx.x;
  if (c >= K_CODES) return;
  const float4* e4 = reinterpret_cast<const float4*>(E + c * D_DIM);
  float s = 0.f;
#pragma unroll
  for (int j = 0; j < 16; ++j) {
    float4 v = e4[j];
    s += v.x * v.x + v.y * v.y + v.z * v.z + v.w * v.w;
  }
  esq[c] = s;
}

// ---------------- K1: K-split distances, top-3 partials ----------------
__global__ __launch_bounds__(256, 4) void k_assign(
    const float* __restrict__ Z, const float* __restrict__ E,
    const float* __restrict__ esq, float* __restrict__ part) {
  __shared__ float sE[CHUNK * D_DIM];
  __shared__ float sQ[CHUNK];
  const int split = blockIdx.x & (KSPLIT - 1);
  const int n = (blockIdx.x >> 2) * 256 + threadIdx.x;
  const int zbase = (n >> 12) * BSTRIDE + (n & 4095);

  float zr[64];
#pragma unroll
  for (int d = 0; d < 64; ++d) zr[d] = Z[zbase + d * HW];
  float zsq = 0.f;
#pragma unroll
  for (int d = 0; d < 64; ++d) zsq = fmaf(zr[d], zr[d], zsq);

  float b1 = 3.4e38f, b2 = 3.4e38f, b3 = 3.4e38f;
  int i1 = 0, i2 = 0;
  const int c00 = split * CODES_PER;

  for (int ch = 0; ch < CODES_PER / CHUNK; ++ch) {
    const int cbase = c00 + ch * CHUNK;
    __syncthreads();
#pragma unroll
    for (int j = 0; j < 8; ++j) {
      const float* gsrc = E + cbase * D_DIM + j * 1024 + threadIdx.x * 4;
      float* ldst = sE + j * 1024 + threadIdx.x * 4;
      __builtin_amdgcn_global_load_lds(
          (const __attribute__((address_space(1))) float*)gsrc,
          (__attribute__((address_space(3))) float*)ldst, 16, 0, 0);
    }
    if (threadIdx.x < CHUNK) sQ[threadIdx.x] = esq[cbase + threadIdx.x];
    __syncthreads();

    for (int c = 0; c < CHUNK; ++c) {
      const float4* ep = reinterpret_cast<const float4*>(sE + c * D_DIM);
      float d0 = 0.f, d1 = 0.f, d2 = 0.f, d3 = 0.f;
#pragma unroll
      for (int j = 0; j < 16; ++j) {
        float4 v = ep[j];
        d0 = fmaf(zr[4 * j + 0], v.x, d0);
        d1 = fmaf(zr[4 * j + 1], v.y, d1);
        d2 = fmaf(zr[4 * j + 2], v.z, d2);
        d3 = fmaf(zr[4 * j + 3], v.w, d3);
      }
      float dist = zsq + sQ[c] - 2.f * ((d0 + d1) + (d2 + d3));
      int cg = cbase + c;
      bool lt1 = dist < b1, lt2 = dist < b2, lt3 = dist < b3;
      b3 = lt2 ? b2 : (lt3 ? dist : b3);
      b2 = lt1 ? b1 : (lt2 ? dist : b2);
      i2 = lt1 ? i1 : (lt2 ? cg : i2);
      b1 = lt1 ? dist : b1;
      i1 = lt1 ? cg : i1;
    }
  }
  const int o = split * N_PTS + n;
  part[o]           = b1;
  part[KSN + o]     = (float)i1;
  part[2 * KSN + o] = b2;
  part[3 * KSN + o] = (float)i2;
  part[4 * KSN + o] = b3;
}

// ---------------- K2: merge partials, tie-resolve, gather/eq/loss ----------------
__global__ __launch_bounds__(256) void k_combine(
    const float* __restrict__ Z, const float* __restrict__ E,
    const float* __restrict__ part,
    float* __restrict__ eq_out, float* __restrict__ idx_out,
    float* __restrict__ counts, float* __restrict__ loss_acc,
    float* __restrict__ zt) {
  __shared__ float lred[4];
  const int n = blockIdx.x * 256 + threadIdx.x;
  const int zbase = (n >> 12) * BSTRIDE + (n & 4095);

  float dd[12], ii[12];
#pragma unroll
  for (int s = 0; s < KSPLIT; ++s) {
    int o = s * N_PTS + n;
    dd[3 * s + 0] = part[o];            ii[3 * s + 0] = part[KSN + o];
    dd[3 * s + 1] = part[2 * KSN + o];  ii[3 * s + 1] = part[3 * KSN + o];
    dd[3 * s + 2] = part[4 * KSN + o];  ii[3 * s + 2] = -1.f;
  }
  float w1 = 3.4e38f, w2 = 3.4e38f, w3 = 3.4e38f;
  int j1 = -1, j2 = -1, i1g = 0, i2g = 0;
#pragma unroll
  for (int j = 0; j < 12; ++j) if (dd[j] < w1) { w1 = dd[j]; i1g = (int)ii[j]; j1 = j; }
#pragma unroll
  for (int j = 0; j < 12; ++j) if (j != j1 && dd[j] < w2) { w2 = dd[j]; i2g = (int)ii[j]; j2 = j; }
#pragma unroll
  for (int j = 0; j < 12; ++j) if (j != j1 && j != j2 && dd[j] < w3) w3 = dd[j];
  if (i2g < 0) i2g = i1g;

  float zr[64];
#pragma unroll
  for (int d = 0; d < 64; ++d) zr[d] = Z[zbase + d * HW];

  // transposed copy for k_update's coalesced per-point gathers
  if (zt) {
    float4* zt4 = reinterpret_cast<float4*>(zt + (size_t)n * 64);
#pragma unroll
    for (int j = 0; j < 16; ++j)
      zt4[j] = make_float4(zr[4 * j + 0], zr[4 * j + 1], zr[4 * j + 2], zr[4 * j + 3]);
  }

  int bi = i1g;
  if (w3 - w1 < M_FULL) {
    double b = 1e300; int bb = 0;
    for (int c = 0; c < K_CODES; ++c) {
      const float* ep = E + c * D_DIM;
      double s = 0.0;
      for (int d = 0; d < 64; ++d) {
        double v = (double)zr[d] - (double)ep[d];
        s += v * v;
      }
      if (s < b) { b = s; bb = c; }
    }
    bi = bb;
  } else if (w2 - w1 < M_RESCORE) {
    const float* ea = E + i1g * D_DIM;
    const float* eb = E + i2g * D_DIM;
    double da = 0.0, db = 0.0;
#pragma unroll
    for (int d = 0; d < 64; ++d) {
      double va = (double)zr[d] - (double)ea[d]; da += va * va;
      double vb = (double)zr[d] - (double)eb[d]; db += vb * vb;
    }
    if (db < da || (db == da && i2g < i1g)) bi = i2g;
  }

  idx_out[n] = (float)bi;
  atomicAdd(&counts[bi], 1.0f);

  const float4* er = reinterpret_cast<const float4*>(E + bi * D_DIM);
  float lsum = 0.f;
#pragma unroll
  for (int j = 0; j < 16; ++j) {
    float4 ev = er[j];
    int d = 4 * j;
    eq_out[zbase + (d + 0) * HW] = ev.x;
    eq_out[zbase + (d + 1) * HW] = ev.y;
    eq_out[zbase + (d + 2) * HW] = ev.z;
    eq_out[zbase + (d + 3) * HW] = ev.w;
    float f0 = ev.x - zr[d + 0], f1 = ev.y - zr[d + 1];
    float f2 = ev.z - zr[d + 2], f3 = ev.w - zr[d + 3];
    lsum = fmaf(f0, f0, lsum); lsum = fmaf(f1, f1, lsum);
    lsum = fmaf(f2, f2, lsum); lsum = fmaf(f3, f3, lsum);
  }
#pragma unroll
  for (int off = 32; off >= 1; off >>= 1) lsum += __shfl_xor(lsum, off, 64);
  int lane = threadIdx.x & 63, wid = threadIdx.x >> 6;
  if (lane == 0) lred[wid] = lsum;
  __syncthreads();
  if (threadIdx.x == 0)
    atomicAdd(loss_acc, lred[0] + lred[1] + lred[2] + lred[3]);
}

// ---------------- fallback: single-pass assign (if ws too small) ----------------
__global__ __launch_bounds__(256) void k_solo(
    const float* __restrict__ Z, const float* __restrict__ E,
    const float* __restrict__ esq,
    float* __restrict__ eq_out, float* __restrict__ idx_out,
    float* __restrict__ counts, float* __restrict__ loss_acc) {
  __shared__ float sE[CHUNK * D_DIM];
  __shared__ float sQ[CHUNK];
  int n = blockIdx.x * 256 + threadIdx.x;
  int zbase = (n >> 12) * BSTRIDE + (n & 4095);

  float zr[64];
#pragma unroll
  for (int d = 0; d < 64; ++d) zr[d] = Z[zbase + d * HW];
  float zsq = 0.f;
#pragma unroll
  for (int d = 0; d < 64; ++d) zsq = fmaf(zr[d], zr[d], zsq);

  float b1 = 3.4e38f, b2 = 3.4e38f, b3 = 3.4e38f;
  int i1 = 0, i2 = 0;
  for (int ch = 0; ch < K_CODES / CHUNK; ++ch) {
    __syncthreads();
    const float4* src = reinterpret_cast<const float4*>(E + ch * CHUNK * D_DIM);
    float4* dst = reinterpret_cast<float4*>(sE);
#pragma unroll
    for (int j = 0; j < 8; ++j) dst[threadIdx.x + 256 * j] = src[threadIdx.x + 256 * j];
    if (threadIdx.x < CHUNK) sQ[threadIdx.x] = esq[ch * CHUNK + threadIdx.x];
    __syncthreads();
    for (int c = 0; c < CHUNK; ++c) {
      const float4* ep = reinterpret_cast<const float4*>(sE + c * D_DIM);
      float d0 = 0.f, d1 = 0.f, d2 = 0.f, d3 = 0.f;
#pragma unroll
      for (int j = 0; j < 16; ++j) {
        float4 v = ep[j];
        d0 = fmaf(zr[4 * j + 0], v.x, d0);
        d1 = fmaf(zr[4 * j + 1], v.y, d1);
        d2 = fmaf(zr[4 * j + 2], v.z, d2);
        d3 = fmaf(zr[4 * j + 3], v.w, d3);
      }
      float dist = zsq + sQ[c] - 2.f * ((d0 + d1) + (d2 + d3));
      int cg = ch * CHUNK + c;
      bool lt1 = dist < b1, lt2 = dist < b2, lt3 = dist < b3;
      b3 = lt2 ? b2 : (lt3 ? dist : b3);
      b2 = lt1 ? b1 : (lt2 ? dist : b2);
      i2 = lt1 ? i1 : (lt2 ? cg : i2);
      b1 = lt1 ? dist : b1;
      i1 = lt1 ? cg : i1;
    }
  }
  int bi = i1;
  if (b3 - b1 < M_FULL) {
    double b = 1e300; int bb = 0;
    for (int c = 0; c < K_CODES; ++c) {
      const float* ep = E + c * D_DIM;
      double s = 0.0;
      for (int d = 0; d < 64; ++d) { double v = (double)zr[d] - (double)ep[d]; s += v * v; }
      if (s < b) { b = s; bb = c; }
    }
    bi = bb;
  } else if (b2 - b1 < M_RESCORE) {
    const float* ea = E + i1 * D_DIM;
    const float* eb = E + i2 * D_DIM;
    double da = 0.0, db = 0.0;
#pragma unroll
    for (int d = 0; d < 64; ++d) {
      double va = (double)zr[d] - (double)ea[d]; da += va * va;
      double vb = (double)zr[d] - (double)eb[d]; db += vb * vb;
    }
    if (db < da || (db == da && i2 < i1)) bi = i2;
  }

  idx_out[n] = (float)bi;
  atomicAdd(&counts[bi], 1.0f);
  const float4* er = reinterpret_cast<const float4*>(E + bi * D_DIM);
  float lsum = 0.f;
#pragma unroll
  for (int j = 0; j < 16; ++j) {
    float4 ev = er[j];
    int d = 4 * j;
    eq_out[zbase + (d + 0) * HW] = ev.x;
    eq_out[zbase + (d + 1) * HW] = ev.y;
    eq_out[zbase + (d + 2) * HW] = ev.z;
    eq_out[zbase + (d + 3) * HW] = ev.w;
    float f0 = ev.x - zr[d + 0], f1 = ev.y - zr[d + 1];
    float f2 = ev.z - zr[d + 2], f3 = ev.w - zr[d + 3];
    lsum = fmaf(f0, f0, lsum); lsum = fmaf(f1, f1, lsum);
    lsum = fmaf(f2, f2, lsum); lsum = fmaf(f3, f3, lsum);
  }
#pragma unroll
  for (int off = 32; off >= 1; off >>= 1) lsum += __shfl_xor(lsum, off, 64);
  if ((threadIdx.x & 63) == 0) atomicAdd(loss_acc, lsum);
}

// ---------------- K3: stats, smoothing scalars, threefry ----------------
__global__ __launch_bounds__(1024) void k_stats(
    const float* __restrict__ counts, const float* __restrict__ cluster_size,
    float* __restrict__ out, float* __restrict__ ws,
    unsigned* __restrict__ rnd, const float* __restrict__ loss_acc) {
  __shared__ float red[16][4];
  int c = threadIdx.x;
  float cnt = counts[c];
  float csb = cluster_size[c] * 0.99f + cnt * 0.01f;
  out[OFF_CSB + c] = csb;

  float v_n = csb;
  float v_s = csb + 1e-5f;
  float p = cnt * (1.0f / 65536.0f);
  float v_p = p * logf(p + 1e-10f);
  float v_u = cnt > 0.f ? 1.f : 0.f;
#pragma unroll
  for (int off = 32; off >= 1; off >>= 1) {
    v_n += __shfl_xor(v_n, off, 64);
    v_s += __shfl_xor(v_s, off, 64);
    v_p += __shfl_xor(v_p, off, 64);
    v_u += __shfl_xor(v_u, off, 64);
  }
  int lane = threadIdx.x & 63, wid = threadIdx.x >> 6;
  if (lane == 0) { red[wid][0] = v_n; red[wid][1] = v_s; red[wid][2] = v_p; red[wid][3] = v_u; }
  __syncthreads();
  if (threadIdx.x == 0) {
    float nsum = 0.f, ssum = 0.f, psum = 0.f, usum = 0.f;
    for (int w = 0; w < 16; ++w) {
      nsum += red[w][0]; ssum += red[w][1]; psum += red[w][2]; usum += red[w][3];
    }
    ws[WS_NVAL] = nsum;
    ws[WS_SCS]  = ssum;
    out[OFF_STATS + 0] = expf(-psum);
    out[OFF_STATS + 1] = usum;
    out[OFF_LOSS] = 1.25f * loss_acc[0] * (1.0f / 4194304.0f);
  }
  rnd[c] = tf_rand_bits(c) & 0xFFFFu;
}

// ---------------- K4 fast: 4-wave ballot scan over z_t ----------------
__global__ __launch_bounds__(256) void k_update2(
    const float* __restrict__ zt, const float* __restrict__ embed_avg,
    const float* __restrict__ ws, const unsigned* __restrict__ rnd,
    const float* __restrict__ idxf, float* __restrict__ out) {
  __shared__ float sm[4][64];
  const int c = blockIdx.x;
  const int d = threadIdx.x & 63, w = threadIdx.x >> 6;
  const float cf = (float)c;
  float es = 0.f;
  const float4* i4 = reinterpret_cast<const float4*>(idxf);
  const int it0 = w * 64, it1 = it0 + 64;
  float4 cur = i4[it0 * 64 + d];
  for (int it = it0; it < it1; ++it) {
    float4 nxt = cur;
    if (it + 1 < it1) nxt = i4[(it + 1) * 64 + d];
    unsigned long long m0 = __ballot(cur.x == cf);
    unsigned long long m1 = __ballot(cur.y == cf);
    unsigned long long m2 = __ballot(cur.z == cf);
    unsigned long long m3 = __ballot(cur.w == cf);
    while (m0) { int b = __ffsll(m0) - 1; m0 &= m0 - 1;
      size_t p = (size_t)(it * 256 + b * 4 + 0); es += zt[p * 64 + d]; }
    while (m1) { int b = __ffsll(m1) - 1; m1 &= m1 - 1;
      size_t p = (size_t)(it * 256 + b * 4 + 1); es += zt[p * 64 + d]; }
    while (m2) { int b = __ffsll(m2) - 1; m2 &= m2 - 1;
      size_t p = (size_t)(it * 256 + b * 4 + 2); es += zt[p * 64 + d]; }
    while (m3) { int b = __ffsll(m3) - 1; m3 &= m3 - 1;
      size_t p = (size_t)(it * 256 + b * 4 + 3); es += zt[p * 64 + d]; }
    cur = nxt;
  }
  sm[w][d] = es;
  __syncthreads();
  if (w == 0) {
    es = ((sm[0][d] + sm[1][d]) + sm[2][d]) + sm[3][d];
    float csb = out[OFF_CSB + c];
    float nval = ws[WS_NVAL], scs = ws[WS_SCS];
    float cs = (csb + 1e-5f) / fmaxf(scs, 1e-8f) * nval;
    bool dead = cs < 1.0f;
    float csf = dead ? 1.0f : cs;
    float ea_ema = embed_avg[c * D_DIM + d] * 0.99f + es * 0.01f;
    int r = (int)rnd[c];
    float zv = zt[(size_t)r * 64 + d];
    float ea = dead ? zv : ea_ema;
    out[OFF_EAB + c * D_DIM + d] = ea;
    out[OFF_EMB + c * D_DIM + d] = ea / csf;
  }
}

// ---------------- K4 slow fallback: strided Z gather ----------------
__global__ __launch_bounds__(64) void k_update_slow(
    const float* __restrict__ Z, const float* __restrict__ embed_avg,
    const float* __restrict__ ws, const unsigned* __restrict__ rnd,
    const float* __restrict__ idxf, float* __restrict__ out) {
  const int c = blockIdx.x, d = threadIdx.x;
  const float cf = (float)c;
  float es = 0.f;
  const float4* i4 = reinterpret_cast<const float4*>(idxf);
  float4 cur = i4[d];
  for (int it = 0; it < 256; ++it) {
    float4 nxt = cur;
    if (it < 255) nxt = i4[(it + 1) * 64 + d];
    unsigned long long m0 = __ballot(cur.x == cf);
    unsigned long long m1 = __ballot(cur.y == cf);
    unsigned long long m2 = __ballot(cur.z == cf);
    unsigned long long m3 = __ballot(cur.w == cf);
    while (m0) { int b = __ffsll(m0) - 1; m0 &= m0 - 1;
      int p = it * 256 + b * 4 + 0; es += Z[(p >> 12) * BSTRIDE + d * HW + (p & 4095)]; }
    while (m1) { int b = __ffsll(m1) - 1; m1 &= m1 - 1;
      int p = it * 256 + b * 4 + 1; es += Z[(p >> 12) * BSTRIDE + d * HW + (p & 4095)]; }
    while (m2) { int b = __ffsll(m2) - 1; m2 &= m2 - 1;
      int p = it * 256 + b * 4 + 2; es += Z[(p >> 12) * BSTRIDE + d * HW + (p & 4095)]; }
    while (m3) { int b = __ffsll(m3) - 1; m3 &= m3 - 1;
      int p = it * 256 + b * 4 + 3; es += Z[(p >> 12) * BSTRIDE + d * HW + (p & 4095)]; }
    cur = nxt;
  }
  float csb = out[OFF_CSB + c];
  float nval = ws[WS_NVAL], scs = ws[WS_SCS];
  float cs = (csb + 1e-5f) / fmaxf(scs, 1e-8f) * nval;
  bool dead = cs < 1.0f;
  float csf = dead ? 1.0f : cs;
  float ea_ema = embed_avg[c * D_DIM + d] * 0.99f + es * 0.01f;
  int r = (int)rnd[c];
  float zv = Z[(r >> 12) * BSTRIDE + d * HW + (r & 4095)];
  float ea = dead ? zv : ea_ema;
  out[OFF_EAB + c * D_DIM + d] = ea;
  out[OFF_EMB + c * D_DIM + d] = ea / csf;
}

extern "C" void kernel_launch(void* const* d_in, const int* in_sizes, int n_in,
                              void* d_out, int out_size, void* d_ws, size_t ws_size,
                              hipStream_t stream) {
  const float* Z  = (const float*)d_in[0];
  const float* E  = (const float*)d_in[1];
  const float* CS = (const float*)d_in[2];
  const float* EA = (const float*)d_in[3];
  float* out = (float*)d_out;
  float* ws  = (float*)d_ws;
  unsigned* rnd = (unsigned*)(ws + WS_RAND);

  const size_t need1 = (size_t)(WS_PART + 5 * KSN + 16) * sizeof(float);
  const size_t need2 = (size_t)(WS_ZT + N_PTS * D_DIM + 16) * sizeof(float);
  const bool big  = ws_size >= need1;
  const bool bigz = ws_size >= need2;
  float* zt = bigz ? (ws + WS_ZT) : nullptr;

  hipMemsetAsync(ws, 0, 1028 * sizeof(float), stream);
  k_esq<<<4, 256, 0, stream>>>(E, ws + WS_ESQ);
  if (big) {
    k_assign<<<N_PTS / 256 * KSPLIT, 256, 0, stream>>>(Z, E, ws + WS_ESQ, ws + WS_PART);
    k_combine<<<N_PTS / 256, 256, 0, stream>>>(Z, E, ws + WS_PART,
                                               out + OFF_EQ, out + OFF_IDX,
                                               ws + WS_CNT, ws + WS_LOSS, zt);
  } else {
    k_solo<<<N_PTS / 256, 256, 0, stream>>>(Z, E, ws + WS_ESQ,
                                            out + OFF_EQ, out + OFF_IDX,
                                            ws + WS_CNT, ws + WS_LOSS);
  }
  k_stats<<<1, 1024, 0, stream>>>(ws + WS_CNT, CS, out, ws, rnd, ws + WS_LOSS);
  if (bigz) {
    k_update2<<<K_CODES, 256, 0, stream>>>(zt, EA, ws, rnd, out + OFF_IDX, out);
  } else {
    k_update_slow<<<K_CODES, 64, 0, stream>>>(Z, EA, ws, rnd, out + OFF_IDX, out);
  }
}

// Round 4
// 245.677 us; speedup vs baseline: 5.6750x; 1.0525x over previous
//
#include <hip/hip_runtime.h>
#include <math.h>

#define K_CODES 1024
#define D_DIM   64
#define N_PTS   65536
#define HW      4096
#define BSTRIDE 262144   // 64*4096 elements per batch image
#define KSPLIT  4
#define CODES_PER (K_CODES / KSPLIT)   // 256
#define CHUNK   128
#define KSN     (KSPLIT * N_PTS)       // 262144

// output offsets (floats)
#define OFF_EQ    0
#define OFF_IDX   4194304
#define OFF_LOSS  4259840
#define OFF_STATS 4259841
#define OFF_EMB   4259843
#define OFF_CSB   4325379
#define OFF_EAB   4326403

// workspace layout (float slots)
#define WS_LOSS 0
#define WS_NVAL 1
#define WS_SCS  2
#define WS_CNT  4
#define WS_ESQ  1028
#define WS_RAND 2052
#define WS_PART 3076
// partial arrays: PB1 @ +0, PI1 @ +KSN, PB2 @ +2*KSN, PI2 @ +3*KSN, PB3 @ +4*KSN
#define WS_ZT   (WS_PART + 5 * KSN)    // transposed z: [N][64]

#define M_RESCORE 0.01f
#define M_FULL    5e-4f

// ---------------- threefry2x32 (JAX-compatible) ----------------
__device__ __forceinline__ void tf_block(unsigned k0, unsigned k1,
                                         unsigned& x0, unsigned& x1) {
  unsigned ks2 = k0 ^ k1 ^ 0x1BD11BDAu;
  x0 += k0; x1 += k1;
#define RR(r) { x0 += x1; x1 = (x1 << r) | (x1 >> (32 - r)); x1 ^= x0; }
  RR(13) RR(15) RR(26) RR(6)
  x0 += k1; x1 += ks2 + 1u;
  RR(17) RR(29) RR(16) RR(24)
  x0 += ks2; x1 += k0 + 2u;
  RR(13) RR(15) RR(26) RR(6)
  x0 += k0; x1 += k1 + 3u;
  RR(17) RR(29) RR(16) RR(24)
  x0 += k1; x1 += ks2 + 4u;
  RR(13) RR(15) RR(26) RR(6)
  x0 += ks2; x1 += k0 + 5u;
#undef RR
}

__device__ __forceinline__ unsigned tf_rand_bits(int c) {
  unsigned a0 = 0u, a1 = 2u; tf_block(0u, 1u, a0, a1);
  unsigned b0 = 1u, b1 = 3u; tf_block(0u, 1u, b0, b1);
  unsigned K0 = a1, K1 = b1;
  unsigned x0, x1;
  if (c < 512) { x0 = (unsigned)c; x1 = (unsigned)(512 + c); tf_block(K0, K1, x0, x1); return x0; }
  else         { x0 = (unsigned)(c - 512); x1 = (unsigned)c; tf_block(K0, K1, x0, x1); return x1; }
}

// ---------------- K0: codebook squared norms ----------------
__global__ void k_esq(const float* __restrict__ E, float* __restrict__ esq) {
  int c = blockIdx.x * blockDim.x + threadIdx.x;
  if (c >= K_CODES) return;
  const float4* e4 = reinterpret_cast<const float4*>(E + c * D_DIM);
  float s = 0.f;
#pragma unroll
  for (int j = 0; j < 16; ++j) {
    float4 v = e4[j];
    s += v.x * v.x + v.y * v.y + v.z * v.z + v.w * v.w;
  }
  esq[c] = s;
}

// ---------------- K1: K-split distances, 2 points/thread, top-3 partials ----------------
__global__ __launch_bounds__(256, 2) void k_assign(
    const float* __restrict__ Z, const float* __restrict__ E,
    const float* __restrict__ esq, float* __restrict__ part) {
  __shared__ float sE[CHUNK * D_DIM];
  __shared__ float sQ[CHUNK];
  const int split = blockIdx.x & (KSPLIT - 1);
  const int n0 = (blockIdx.x >> 2) * 512 + threadIdx.x;
  const int n1 = n0 + 256;
  const int zb0 = (n0 >> 12) * BSTRIDE + (n0 & 4095);
  const int zb1 = (n1 >> 12) * BSTRIDE + (n1 & 4095);

  float zr0[64], zr1[64];
#pragma unroll
  for (int d = 0; d < 64; ++d) zr0[d] = Z[zb0 + d * HW];
#pragma unroll
  for (int d = 0; d < 64; ++d) zr1[d] = Z[zb1 + d * HW];
  float zsq0 = 0.f, zsq1 = 0.f;
#pragma unroll
  for (int d = 0; d < 64; ++d) zsq0 = fmaf(zr0[d], zr0[d], zsq0);
#pragma unroll
  for (int d = 0; d < 64; ++d) zsq1 = fmaf(zr1[d], zr1[d], zsq1);

  float a1 = 3.4e38f, a2 = 3.4e38f, a3 = 3.4e38f;   // point 0 top-3
  int ai1 = 0, ai2 = 0;
  float c1 = 3.4e38f, c2 = 3.4e38f, c3 = 3.4e38f;   // point 1 top-3
  int ci1 = 0, ci2 = 0;
  const int c00 = split * CODES_PER;

  for (int ch = 0; ch < CODES_PER / CHUNK; ++ch) {
    const int cbase = c00 + ch * CHUNK;
    __syncthreads();
#pragma unroll
    for (int j = 0; j < 8; ++j) {
      const float* gsrc = E + cbase * D_DIM + j * 1024 + threadIdx.x * 4;
      float* ldst = sE + j * 1024 + threadIdx.x * 4;
      __builtin_amdgcn_global_load_lds(
          (const __attribute__((address_space(1))) float*)gsrc,
          (__attribute__((address_space(3))) float*)ldst, 16, 0, 0);
    }
    if (threadIdx.x < CHUNK) sQ[threadIdx.x] = esq[cbase + threadIdx.x];
    __syncthreads();

    for (int c = 0; c < CHUNK; ++c) {
      const float4* ep = reinterpret_cast<const float4*>(sE + c * D_DIM);
      float p00 = 0.f, p01 = 0.f, p02 = 0.f, p03 = 0.f;
      float p10 = 0.f, p11 = 0.f, p12 = 0.f, p13 = 0.f;
#pragma unroll
      for (int j = 0; j < 16; ++j) {
        float4 v = ep[j];
        p00 = fmaf(zr0[4 * j + 0], v.x, p00);
        p01 = fmaf(zr0[4 * j + 1], v.y, p01);
        p02 = fmaf(zr0[4 * j + 2], v.z, p02);
        p03 = fmaf(zr0[4 * j + 3], v.w, p03);
        p10 = fmaf(zr1[4 * j + 0], v.x, p10);
        p11 = fmaf(zr1[4 * j + 1], v.y, p11);
        p12 = fmaf(zr1[4 * j + 2], v.z, p12);
        p13 = fmaf(zr1[4 * j + 3], v.w, p13);
      }
      float q = sQ[c];
      int cg = cbase + c;
      float dist0 = zsq0 + q - 2.f * ((p00 + p01) + (p02 + p03));
      float dist1 = zsq1 + q - 2.f * ((p10 + p11) + (p12 + p13));
      {
        bool lt1 = dist0 < a1, lt2 = dist0 < a2, lt3 = dist0 < a3;
        a3 = lt2 ? a2 : (lt3 ? dist0 : a3);
        a2 = lt1 ? a1 : (lt2 ? dist0 : a2);
        ai2 = lt1 ? ai1 : (lt2 ? cg : ai2);
        a1 = lt1 ? dist0 : a1;
        ai1 = lt1 ? cg : ai1;
      }
      {
        bool lt1 = dist1 < c1, lt2 = dist1 < c2, lt3 = dist1 < c3;
        c3 = lt2 ? c2 : (lt3 ? dist1 : c3);
        c2 = lt1 ? c1 : (lt2 ? dist1 : c2);
        ci2 = lt1 ? ci1 : (lt2 ? cg : ci2);
        c1 = lt1 ? dist1 : c1;
        ci1 = lt1 ? cg : ci1;
      }
    }
  }
  const int o0 = split * N_PTS + n0;
  const int o1 = split * N_PTS + n1;
  part[o0]           = a1;
  part[KSN + o0]     = (float)ai1;
  part[2 * KSN + o0] = a2;
  part[3 * KSN + o0] = (float)ai2;
  part[4 * KSN + o0] = a3;
  part[o1]           = c1;
  part[KSN + o1]     = (float)ci1;
  part[2 * KSN + o1] = c2;
  part[3 * KSN + o1] = (float)ci2;
  part[4 * KSN + o1] = c3;
}

// ---------------- K2: merge partials, tie-resolve, gather/eq/loss ----------------
__global__ __launch_bounds__(256) void k_combine(
    const float* __restrict__ Z, const float* __restrict__ E,
    const float* __restrict__ part,
    float* __restrict__ eq_out, float* __restrict__ idx_out,
    float* __restrict__ counts, float* __restrict__ loss_acc,
    float* __restrict__ zt) {
  __shared__ float lred[4];
  const int n = blockIdx.x * 256 + threadIdx.x;
  const int zbase = (n >> 12) * BSTRIDE + (n & 4095);

  float dd[12], ii[12];
#pragma unroll
  for (int s = 0; s < KSPLIT; ++s) {
    int o = s * N_PTS + n;
    dd[3 * s + 0] = part[o];            ii[3 * s + 0] = part[KSN + o];
    dd[3 * s + 1] = part[2 * KSN + o];  ii[3 * s + 1] = part[3 * KSN + o];
    dd[3 * s + 2] = part[4 * KSN + o];  ii[3 * s + 2] = -1.f;
  }
  float w1 = 3.4e38f, w2 = 3.4e38f, w3 = 3.4e38f;
  int j1 = -1, j2 = -1, i1g = 0, i2g = 0;
#pragma unroll
  for (int j = 0; j < 12; ++j) if (dd[j] < w1) { w1 = dd[j]; i1g = (int)ii[j]; j1 = j; }
#pragma unroll
  for (int j = 0; j < 12; ++j) if (j != j1 && dd[j] < w2) { w2 = dd[j]; i2g = (int)ii[j]; j2 = j; }
#pragma unroll
  for (int j = 0; j < 12; ++j) if (j != j1 && j != j2 && dd[j] < w3) w3 = dd[j];
  if (i2g < 0) i2g = i1g;

  float zr[64];
#pragma unroll
  for (int d = 0; d < 64; ++d) zr[d] = Z[zbase + d * HW];

  if (zt) {
    float4* zt4 = reinterpret_cast<float4*>(zt + (size_t)n * 64);
#pragma unroll
    for (int j = 0; j < 16; ++j)
      zt4[j] = make_float4(zr[4 * j + 0], zr[4 * j + 1], zr[4 * j + 2], zr[4 * j + 3]);
  }

  int bi = i1g;
  if (w3 - w1 < M_FULL) {
    double b = 1e300; int bb = 0;
    for (int c = 0; c < K_CODES; ++c) {
      const float* ep = E + c * D_DIM;
      double s = 0.0;
      for (int d = 0; d < 64; ++d) {
        double v = (double)zr[d] - (double)ep[d];
        s += v * v;
      }
      if (s < b) { b = s; bb = c; }
    }
    bi = bb;
  } else if (w2 - w1 < M_RESCORE) {
    const float* ea = E + i1g * D_DIM;
    const float* eb = E + i2g * D_DIM;
    double da = 0.0, db = 0.0;
#pragma unroll
    for (int d = 0; d < 64; ++d) {
      double va = (double)zr[d] - (double)ea[d]; da += va * va;
      double vb = (double)zr[d] - (double)eb[d]; db += vb * vb;
    }
    if (db < da || (db == da && i2g < i1g)) bi = i2g;
  }

  idx_out[n] = (float)bi;
  atomicAdd(&counts[bi], 1.0f);

  const float4* er = reinterpret_cast<const float4*>(E + bi * D_DIM);
  float lsum = 0.f;
#pragma unroll
  for (int j = 0; j < 16; ++j) {
    float4 ev = er[j];
    int d = 4 * j;
    eq_out[zbase + (d + 0) * HW] = ev.x;
    eq_out[zbase + (d + 1) * HW] = ev.y;
    eq_out[zbase + (d + 2) * HW] = ev.z;
    eq_out[zbase + (d + 3) * HW] = ev.w;
    float f0 = ev.x - zr[d + 0], f1 = ev.y - zr[d + 1];
    float f2 = ev.z - zr[d + 2], f3 = ev.w - zr[d + 3];
    lsum = fmaf(f0, f0, lsum); lsum = fmaf(f1, f1, lsum);
    lsum = fmaf(f2, f2, lsum); lsum = fmaf(f3, f3, lsum);
  }
#pragma unroll
  for (int off = 32; off >= 1; off >>= 1) lsum += __shfl_xor(lsum, off, 64);
  int lane = threadIdx.x & 63, wid = threadIdx.x >> 6;
  if (lane == 0) lred[wid] = lsum;
  __syncthreads();
  if (threadIdx.x == 0)
    atomicAdd(loss_acc, lred[0] + lred[1] + lred[2] + lred[3]);
}

// ---------------- fallback: single-pass assign (if ws too small) ----------------
__global__ __launch_bounds__(256) void k_solo(
    const float* __restrict__ Z, const float* __restrict__ E,
    const float* __restrict__ esq,
    float* __restrict__ eq_out, float* __restrict__ idx_out,
    float* __restrict__ counts, float* __restrict__ loss_acc) {
  __shared__ float sE[CHUNK * D_DIM];
  __shared__ float sQ[CHUNK];
  int n = blockIdx.x * 256 + threadIdx.x;
  int zbase = (n >> 12) * BSTRIDE + (n & 4095);

  float zr[64];
#pragma unroll
  for (int d = 0; d < 64; ++d) zr[d] = Z[zbase + d * HW];
  float zsq = 0.f;
#pragma unroll
  for (int d = 0; d < 64; ++d) zsq = fmaf(zr[d], zr[d], zsq);

  float b1 = 3.4e38f, b2 = 3.4e38f, b3 = 3.4e38f;
  int i1 = 0, i2 = 0;
  for (int ch = 0; ch < K_CODES / CHUNK; ++ch) {
    __syncthreads();
    const float4* src = reinterpret_cast<const float4*>(E + ch * CHUNK * D_DIM);
    float4* dst = reinterpret_cast<float4*>(sE);
#pragma unroll
    for (int j = 0; j < 8; ++j) dst[threadIdx.x + 256 * j] = src[threadIdx.x + 256 * j];
    if (threadIdx.x < CHUNK) sQ[threadIdx.x] = esq[ch * CHUNK + threadIdx.x];
    __syncthreads();
    for (int c = 0; c < CHUNK; ++c) {
      const float4* ep = reinterpret_cast<const float4*>(sE + c * D_DIM);
      float d0 = 0.f, d1 = 0.f, d2 = 0.f, d3 = 0.f;
#pragma unroll
      for (int j = 0; j < 16; ++j) {
        float4 v = ep[j];
        d0 = fmaf(zr[4 * j + 0], v.x, d0);
        d1 = fmaf(zr[4 * j + 1], v.y, d1);
        d2 = fmaf(zr[4 * j + 2], v.z, d2);
        d3 = fmaf(zr[4 * j + 3], v.w, d3);
      }
      float dist = zsq + sQ[c] - 2.f * ((d0 + d1) + (d2 + d3));
      int cg = ch * CHUNK + c;
      bool lt1 = dist < b1, lt2 = dist < b2, lt3 = dist < b3;
      b3 = lt2 ? b2 : (lt3 ? dist : b3);
      b2 = lt1 ? b1 : (lt2 ? dist : b2);
      i2 = lt1 ? i1 : (lt2 ? cg : i2);
      b1 = lt1 ? dist : b1;
      i1 = lt1 ? cg : i1;
    }
  }
  int bi = i1;
  if (b3 - b1 < M_FULL) {
    double b = 1e300; int bb = 0;
    for (int c = 0; c < K_CODES; ++c) {
      const float* ep = E + c * D_DIM;
      double s = 0.0;
      for (int d = 0; d < 64; ++d) { double v = (double)zr[d] - (double)ep[d]; s += v * v; }
      if (s < b) { b = s; bb = c; }
    }
    bi = bb;
  } else if (b2 - b1 < M_RESCORE) {
    const float* ea = E + i1 * D_DIM;
    const float* eb = E + i2 * D_DIM;
    double da = 0.0, db = 0.0;
#pragma unroll
    for (int d = 0; d < 64; ++d) {
      double va = (double)zr[d] - (double)ea[d]; da += va * va;
      double vb = (double)zr[d] - (double)eb[d]; db += vb * vb;
    }
    if (db < da || (db == da && i2 < i1)) bi = i2;
  }

  idx_out[n] = (float)bi;
  atomicAdd(&counts[bi], 1.0f);
  const float4* er = reinterpret_cast<const float4*>(E + bi * D_DIM);
  float lsum = 0.f;
#pragma unroll
  for (int j = 0; j < 16; ++j) {
    float4 ev = er[j];
    int d = 4 * j;
    eq_out[zbase + (d + 0) * HW] = ev.x;
    eq_out[zbase + (d + 1) * HW] = ev.y;
    eq_out[zbase + (d + 2) * HW] = ev.z;
    eq_out[zbase + (d + 3) * HW] = ev.w;
    float f0 = ev.x - zr[d + 0], f1 = ev.y - zr[d + 1];
    float f2 = ev.z - zr[d + 2], f3 = ev.w - zr[d + 3];
    lsum = fmaf(f0, f0, lsum); lsum = fmaf(f1, f1, lsum);
    lsum = fmaf(f2, f2, lsum); lsum = fmaf(f3, f3, lsum);
  }
#pragma unroll
  for (int off = 32; off >= 1; off >>= 1) lsum += __shfl_xor(lsum, off, 64);
  if ((threadIdx.x & 63) == 0) atomicAdd(loss_acc, lsum);
}

// ---------------- K3: stats, smoothing scalars, threefry ----------------
__global__ __launch_bounds__(1024) void k_stats(
    const float* __restrict__ counts, const float* __restrict__ cluster_size,
    float* __restrict__ out, float* __restrict__ ws,
    unsigned* __restrict__ rnd, const float* __restrict__ loss_acc) {
  __shared__ float red[16][4];
  int c = threadIdx.x;
  float cnt = counts[c];
  float csb = cluster_size[c] * 0.99f + cnt * 0.01f;
  out[OFF_CSB + c] = csb;

  float v_n = csb;
  float v_s = csb + 1e-5f;
  float p = cnt * (1.0f / 65536.0f);
  float v_p = p * logf(p + 1e-10f);
  float v_u = cnt > 0.f ? 1.f : 0.f;
#pragma unroll
  for (int off = 32; off >= 1; off >>= 1) {
    v_n += __shfl_xor(v_n, off, 64);
    v_s += __shfl_xor(v_s, off, 64);
    v_p += __shfl_xor(v_p, off, 64);
    v_u += __shfl_xor(v_u, off, 64);
  }
  int lane = threadIdx.x & 63, wid = threadIdx.x >> 6;
  if (lane == 0) { red[wid][0] = v_n; red[wid][1] = v_s; red[wid][2] = v_p; red[wid][3] = v_u; }
  __syncthreads();
  if (threadIdx.x == 0) {
    float nsum = 0.f, ssum = 0.f, psum = 0.f, usum = 0.f;
    for (int w = 0; w < 16; ++w) {
      nsum += red[w][0]; ssum += red[w][1]; psum += red[w][2]; usum += red[w][3];
    }
    ws[WS_NVAL] = nsum;
    ws[WS_SCS]  = ssum;
    out[OFF_STATS + 0] = expf(-psum);
    out[OFF_STATS + 1] = usum;
    out[OFF_LOSS] = 1.25f * loss_acc[0] * (1.0f / 4194304.0f);
  }
  rnd[c] = tf_rand_bits(c) & 0xFFFFu;
}

// ---------------- K4 fast: 4-wave ballot scan over z_t ----------------
__global__ __launch_bounds__(256) void k_update2(
    const float* __restrict__ zt, const float* __restrict__ embed_avg,
    const float* __restrict__ ws, const unsigned* __restrict__ rnd,
    const float* __restrict__ idxf, float* __restrict__ out) {
  __shared__ float sm[4][64];
  const int c = blockIdx.x;
  const int d = threadIdx.x & 63, w = threadIdx.x >> 6;
  const float cf = (float)c;
  float es = 0.f;
  const float4* i4 = reinterpret_cast<const float4*>(idxf);
  const int it0 = w * 64, it1 = it0 + 64;
  float4 cur = i4[it0 * 64 + d];
  for (int it = it0; it < it1; ++it) {
    float4 nxt = cur;
    if (it + 1 < it1) nxt = i4[(it + 1) * 64 + d];
    unsigned long long m0 = __ballot(cur.x == cf);
    unsigned long long m1 = __ballot(cur.y == cf);
    unsigned long long m2 = __ballot(cur.z == cf);
    unsigned long long m3 = __ballot(cur.w == cf);
    while (m0) { int b = __ffsll(m0) - 1; m0 &= m0 - 1;
      size_t p = (size_t)(it * 256 + b * 4 + 0); es += zt[p * 64 + d]; }
    while (m1) { int b = __ffsll(m1) - 1; m1 &= m1 - 1;
      size_t p = (size_t)(it * 256 + b * 4 + 1); es += zt[p * 64 + d]; }
    while (m2) { int b = __ffsll(m2) - 1; m2 &= m2 - 1;
      size_t p = (size_t)(it * 256 + b * 4 + 2); es += zt[p * 64 + d]; }
    while (m3) { int b = __ffsll(m3) - 1; m3 &= m3 - 1;
      size_t p = (size_t)(it * 256 + b * 4 + 3); es += zt[p * 64 + d]; }
    cur = nxt;
  }
  sm[w][d] = es;
  __syncthreads();
  if (w == 0) {
    es = ((sm[0][d] + sm[1][d]) + sm[2][d]) + sm[3][d];
    float csb = out[OFF_CSB + c];
    float nval = ws[WS_NVAL], scs = ws[WS_SCS];
    float cs = (csb + 1e-5f) / fmaxf(scs, 1e-8f) * nval;
    bool dead = cs < 1.0f;
    float csf = dead ? 1.0f : cs;
    float ea_ema = embed_avg[c * D_DIM + d] * 0.99f + es * 0.01f;
    int r = (int)rnd[c];
    float zv = zt[(size_t)r * 64 + d];
    float ea = dead ? zv : ea_ema;
    out[OFF_EAB + c * D_DIM + d] = ea;
    out[OFF_EMB + c * D_DIM + d] = ea / csf;
  }
}

// ---------------- K4 slow fallback: strided Z gather ----------------
__global__ __launch_bounds__(64) void k_update_slow(
    const float* __restrict__ Z, const float* __restrict__ embed_avg,
    const float* __restrict__ ws, const unsigned* __restrict__ rnd,
    const float* __restrict__ idxf, float* __restrict__ out) {
  const int c = blockIdx.x, d = threadIdx.x;
  const float cf = (float)c;
  float es = 0.f;
  const float4* i4 = reinterpret_cast<const float4*>(idxf);
  float4 cur = i4[d];
  for (int it = 0; it < 256; ++it) {
    float4 nxt = cur;
    if (it < 255) nxt = i4[(it + 1) * 64 + d];
    unsigned long long m0 = __ballot(cur.x == cf);
    unsigned long long m1 = __ballot(cur.y == cf);
    unsigned long long m2 = __ballot(cur.z == cf);
    unsigned long long m3 = __ballot(cur.w == cf);
    while (m0) { int b = __ffsll(m0) - 1; m0 &= m0 - 1;
      int p = it * 256 + b * 4 + 0; es += Z[(p >> 12) * BSTRIDE + d * HW + (p & 4095)]; }
    while (m1) { int b = __ffsll(m1) - 1; m1 &= m1 - 1;
      int p = it * 256 + b * 4 + 1; es += Z[(p >> 12) * BSTRIDE + d * HW + (p & 4095)]; }
    while (m2) { int b = __ffsll(m2) - 1; m2 &= m2 - 1;
      int p = it * 256 + b * 4 + 2; es += Z[(p >> 12) * BSTRIDE + d * HW + (p & 4095)]; }
    while (m3) { int b = __ffsll(m3) - 1; m3 &= m3 - 1;
      int p = it * 256 + b * 4 + 3; es += Z[(p >> 12) * BSTRIDE + d * HW + (p & 4095)]; }
    cur = nxt;
  }
  float csb = out[OFF_CSB + c];
  float nval = ws[WS_NVAL], scs = ws[WS_SCS];
  float cs = (csb + 1e-5f) / fmaxf(scs, 1e-8f) * nval;
  bool dead = cs < 1.0f;
  float csf = dead ? 1.0f : cs;
  float ea_ema = embed_avg[c * D_DIM + d] * 0.99f + es * 0.01f;
  int r = (int)rnd[c];
  float zv = Z[(r >> 12) * BSTRIDE + d * HW + (r & 4095)];
  float ea = dead ? zv : ea_ema;
  out[OFF_EAB + c * D_DIM + d] = ea;
  out[OFF_EMB + c * D_DIM + d] = ea / csf;
}

extern "C" void kernel_launch(void* const* d_in, const int* in_sizes, int n_in,
                              void* d_out, int out_size, void* d_ws, size_t ws_size,
                              hipStream_t stream) {
  const float* Z  = (const float*)d_in[0];
  const float* E  = (const float*)d_in[1];
  const float* CS = (const float*)d_in[2];
  const float* EA = (const float*)d_in[3];
  float* out = (float*)d_out;
  float* ws  = (float*)d_ws;
  unsigned* rnd = (unsigned*)(ws + WS_RAND);

  const size_t need1 = (size_t)(WS_PART + 5 * KSN + 16) * sizeof(float);
  const size_t need2 = (size_t)(WS_ZT + N_PTS * D_DIM + 16) * sizeof(float);
  const bool big  = ws_size >= need1;
  const bool bigz = ws_size >= need2;
  float* zt = bigz ? (ws + WS_ZT) : nullptr;

  hipMemsetAsync(ws, 0, 1028 * sizeof(float), stream);
  k_esq<<<4, 256, 0, stream>>>(E, ws + WS_ESQ);
  if (big) {
    k_assign<<<N_PTS / 512 * KSPLIT, 256, 0, stream>>>(Z, E, ws + WS_ESQ, ws + WS_PART);
    k_combine<<<N_PTS / 256, 256, 0, stream>>>(Z, E, ws + WS_PART,
                                               out + OFF_EQ, out + OFF_IDX,
                                               ws + WS_CNT, ws + WS_LOSS, zt);
  } else {
    k_solo<<<N_PTS / 256, 256, 0, stream>>>(Z, E, ws + WS_ESQ,
                                            out + OFF_EQ, out + OFF_IDX,
                                            ws + WS_CNT, ws + WS_LOSS);
  }
  k_stats<<<1, 1024, 0, stream>>>(ws + WS_CNT, CS, out, ws, rnd, ws + WS_LOSS);
  if (bigz) {
    k_update2<<<K_CODES, 256, 0, stream>>>(zt, EA, ws, rnd, out + OFF_IDX, out);
  } else {
    k_update_slow<<<K_CODES, 64, 0, stream>>>(Z, EA, ws, rnd, out + OFF_IDX, out);
  }
}

// Round 5
// 157.034 us; speedup vs baseline: 8.8784x; 1.5645x over previous
//
#include <hip/hip_runtime.h>
#include <math.h>

#define K_CODES 1024
#define D_DIM   64
#define N_PTS   65536
#define HW      4096
#define BSTRIDE 262144   // 64*4096 elements per batch image
#define CHUNK   128      // codes per LDS chunk (fp32 fallback + mfma path)

// output offsets (floats)
#define OFF_EQ    0
#define OFF_IDX   4194304
#define OFF_LOSS  4259840
#define OFF_STATS 4259841
#define OFF_EMB   4259843
#define OFF_CSB   4325379
#define OFF_EAB   4326403

// workspace layout (float slots)
#define WS_LOSS 0
#define WS_NVAL 1
#define WS_SCS  2
#define WS_CNT  4
#define WS_ESQ  1028
#define WS_RAND 2052
#define WS_EHI  3076                   // 65536 ushort (32768 float slots), swizzled bf16-hi codebook
#define WS_ELO  35844                  // 65536 ushort, swizzled bf16-lo
#define WS_PART 68612                  // 5 arrays of N: s1,i1,s2,i2,s3
#define WS_ZT   (WS_PART + 5 * N_PTS)  // transposed z: [N][64]

// fp32-exact fallback thresholds
#define M_RESCORE 0.01f
#define M_FULL    5e-4f
// MFMA-approx thresholds (dist error bound ~3e-3)
#define MX_RESCORE 0.05f
#define MX_FULL    8e-3f

typedef __attribute__((ext_vector_type(8))) __bf16 bf16x8;
typedef __attribute__((ext_vector_type(4))) float  f32x4;

// ---------------- bf16 split helpers ----------------
__device__ __forceinline__ unsigned short f2bf_rne(float x) {
  unsigned u = __float_as_uint(x);
  unsigned r = u + 0x7FFFu + ((u >> 16) & 1u);
  return (unsigned short)(r >> 16);
}
__device__ __forceinline__ float bf2f(unsigned short h) {
  return __uint_as_float(((unsigned)h) << 16);
}

// ---------------- threefry2x32 (JAX-compatible) ----------------
__device__ __forceinline__ void tf_block(unsigned k0, unsigned k1,
                                         unsigned& x0, unsigned& x1) {
  unsigned ks2 = k0 ^ k1 ^ 0x1BD11BDAu;
  x0 += k0; x1 += k1;
#define RR(r) { x0 += x1; x1 = (x1 << r) | (x1 >> (32 - r)); x1 ^= x0; }
  RR(13) RR(15) RR(26) RR(6)
  x0 += k1; x1 += ks2 + 1u;
  RR(17) RR(29) RR(16) RR(24)
  x0 += ks2; x1 += k0 + 2u;
  RR(13) RR(15) RR(26) RR(6)
  x0 += k0; x1 += k1 + 3u;
  RR(17) RR(29) RR(16) RR(24)
  x0 += k1; x1 += ks2 + 4u;
  RR(13) RR(15) RR(26) RR(6)
  x0 += ks2; x1 += k0 + 5u;
#undef RR
}

__device__ __forceinline__ unsigned tf_rand_bits(int c) {
  unsigned a0 = 0u, a1 = 2u; tf_block(0u, 1u, a0, a1);
  unsigned b0 = 1u, b1 = 3u; tf_block(0u, 1u, b0, b1);
  unsigned K0 = a1, K1 = b1;
  unsigned x0, x1;
  if (c < 512) { x0 = (unsigned)c; x1 = (unsigned)(512 + c); tf_block(K0, K1, x0, x1); return x0; }
  else         { x0 = (unsigned)(c - 512); x1 = (unsigned)c; tf_block(K0, K1, x0, x1); return x1; }
}

// ---------------- K0: codebook squared norms ----------------
__global__ void k_esq(const float* __restrict__ E, float* __restrict__ esq) {
  int c = blockIdx.x * blockDim.x + threadIdx.x;
  if (c >= K_CODES) return;
  const float4* e4 = reinterpret_cast<const float4*>(E + c * D_DIM);
  float s = 0.f;
#pragma unroll
  for (int j = 0; j < 16; ++j) {
    float4 v = e4[j];
    s += v.x * v.x + v.y * v.y + v.z * v.z + v.w * v.w;
  }
  esq[c] = s;
}

// ---------------- K0b: split codebook into swizzled bf16 hi/lo ----------------
__global__ __launch_bounds__(256) void k_cvt(const float* __restrict__ E,
                                             unsigned short* __restrict__ ehi,
                                             unsigned short* __restrict__ elo) {
  int idx = blockIdx.x * 256 + threadIdx.x;  // 0..65535
  int c = idx >> 6, k = idx & 63;
  float v = E[idx];
  unsigned short h = f2bf_rne(v);
  unsigned short l = f2bf_rne(v - bf2f(h));
  int pos = (c << 6) | (k ^ ((c & 7) << 3));  // XOR-swizzle (16B granules)
  ehi[pos] = h;
  elo[pos] = l;
}

// ---------------- top-3 butterfly merge across 16-lane groups ----------------
__device__ __forceinline__ void merge3(float& a1, float& ai1, float& a2,
                                       float& ai2, float& a3, int off) {
  float b1  = __shfl_xor(a1, off, 64);
  float bi1 = __shfl_xor(ai1, off, 64);
  float b2  = __shfl_xor(a2, off, 64);
  float bi2 = __shfl_xor(ai2, off, 64);
  float b3  = __shfl_xor(a3, off, 64);
  bool f1 = a1 <= b1;
  float m1  = f1 ? a1 : b1;
  float mi1 = f1 ? ai1 : bi1;
  float hi  = f1 ? b1 : a1;
  float hii = f1 ? bi1 : ai1;
  bool f2 = a2 <= b2;
  float c2  = f2 ? a2 : b2;
  float ci2 = f2 ? ai2 : bi2;
  bool f3 = hi <= c2;
  float m2  = f3 ? hi : c2;
  float mi2 = f3 ? hii : ci2;
  float m3  = fminf(fmaxf(hi, c2), fminf(a3, b3));
  a1 = m1; ai1 = mi1; a2 = m2; ai2 = mi2; a3 = m3;
}

// ---------------- K1: MFMA distances, 128 pts/block, all 1024 codes ----------------
__global__ __launch_bounds__(256, 2) void k_assign_mfma(
    const float* __restrict__ Z, const unsigned short* __restrict__ ehi_g,
    const unsigned short* __restrict__ elo_g, const float* __restrict__ esq_g,
    float* __restrict__ part) {
  __shared__ __align__(16) unsigned short zh_s[128 * 64];
  __shared__ __align__(16) unsigned short zl_s[128 * 64];
  __shared__ __align__(16) unsigned short ehi_s[128 * 64];
  __shared__ __align__(16) unsigned short elo_s[128 * 64];
  __shared__ __align__(16) float esq_s[128];

  const int tid  = threadIdx.x;
  const int lane = tid & 63;
  const int wv   = tid >> 6;
  const int bb   = blockIdx.x * 128;          // first point of block
  const int img  = bb >> 12;
  const int pix0 = bb & 4095;

  // ---- stage z: fp32 load (coalesced) -> split bf16 hi/lo -> swizzled LDS ----
  {
    const int pt = tid & 127;
    const int grp = tid >> 7;                 // 0/1: dims 0-31 / 32-63
    const int gb = img * BSTRIDE + pix0 + pt;
    unsigned* zh32 = reinterpret_cast<unsigned*>(zh_s);
    unsigned* zl32 = reinterpret_cast<unsigned*>(zl_s);
    const int sw = (pt & 7) << 3;
#pragma unroll
    for (int it = 0; it < 16; ++it) {
      int k0 = (grp * 16 + it) * 2;
      float v0 = Z[gb + k0 * HW];
      float v1 = Z[gb + (k0 + 1) * HW];
      unsigned short h0 = f2bf_rne(v0);
      unsigned short h1 = f2bf_rne(v1);
      unsigned short l0 = f2bf_rne(v0 - bf2f(h0));
      unsigned short l1 = f2bf_rne(v1 - bf2f(h1));
      int ui = pt * 32 + ((k0 ^ sw) >> 1);
      zh32[ui] = (unsigned)h0 | ((unsigned)h1 << 16);
      zl32[ui] = (unsigned)l0 | ((unsigned)l1 << 16);
    }
  }
  __syncthreads();

  // ---- load A fragments (z) once: 2 row-tiles x {h0,h1,l0,l1} ----
  const int col = lane & 15;
  const int g16 = (lane >> 4) * 16;           // byte offset of k-slot
  bf16x8 a0h0, a0h1, a0l0, a0l1, a1h0, a1h1, a1l0, a1l1;
  {
    const char* zhb = reinterpret_cast<const char*>(zh_s);
    const char* zlb = reinterpret_cast<const char*>(zl_s);
    int pt0 = wv * 32 + col;
    int pt1 = pt0 + 16;
    int sw0 = (pt0 & 7) << 4, sw1 = (pt1 & 7) << 4;
    a0h0 = *reinterpret_cast<const bf16x8*>(zhb + pt0 * 128 + (g16 ^ sw0));
    a0h1 = *reinterpret_cast<const bf16x8*>(zhb + pt0 * 128 + ((64 + g16) ^ sw0));
    a0l0 = *reinterpret_cast<const bf16x8*>(zlb + pt0 * 128 + (g16 ^ sw0));
    a0l1 = *reinterpret_cast<const bf16x8*>(zlb + pt0 * 128 + ((64 + g16) ^ sw0));
    a1h0 = *reinterpret_cast<const bf16x8*>(zhb + pt1 * 128 + (g16 ^ sw1));
    a1h1 = *reinterpret_cast<const bf16x8*>(zhb + pt1 * 128 + ((64 + g16) ^ sw1));
    a1l0 = *reinterpret_cast<const bf16x8*>(zlb + pt1 * 128 + (g16 ^ sw1));
    a1l1 = *reinterpret_cast<const bf16x8*>(zlb + pt1 * 128 + ((64 + g16) ^ sw1));
  }

  // ---- per-lane running top-3 state: [rt][j] ----
  float s1a[2][4], s2a[2][4], s3a[2][4], i1a[2][4], i2a[2][4];
#pragma unroll
  for (int rt = 0; rt < 2; ++rt)
#pragma unroll
    for (int j = 0; j < 4; ++j) {
      s1a[rt][j] = 3.4e38f; s2a[rt][j] = 3.4e38f; s3a[rt][j] = 3.4e38f;
      i1a[rt][j] = 0.f; i2a[rt][j] = 0.f;
    }

  const char* ehb = reinterpret_cast<const char*>(ehi_s);
  const char* elb = reinterpret_cast<const char*>(elo_s);
  const int swc = (col & 7) << 4;

  for (int chunk = 0; chunk < 8; ++chunk) {
    __syncthreads();
    // stage E chunk (pre-swizzled in ws -> linear copy preserves swizzle)
#pragma unroll
    for (int r = 0; r < 4; ++r) {
      const char* srch = reinterpret_cast<const char*>(ehi_g) + chunk * 16384 + (r * 256 + tid) * 16;
      const char* srcl = reinterpret_cast<const char*>(elo_g) + chunk * 16384 + (r * 256 + tid) * 16;
      char* dsth = reinterpret_cast<char*>(ehi_s) + (r * 256 + tid) * 16;
      char* dstl = reinterpret_cast<char*>(elo_s) + (r * 256 + tid) * 16;
      __builtin_amdgcn_global_load_lds(
          (const __attribute__((address_space(1))) float*)srch,
          (__attribute__((address_space(3))) float*)dsth, 16, 0, 0);
      __builtin_amdgcn_global_load_lds(
          (const __attribute__((address_space(1))) float*)srcl,
          (__attribute__((address_space(3))) float*)dstl, 16, 0, 0);
    }
    if (tid < 128) esq_s[tid] = esq_g[chunk * 128 + tid];
    __syncthreads();

    for (int ct = 0; ct < 8; ++ct) {
      const int cl = ct * 16 + col;  // local code = B column
      bf16x8 bh0 = *reinterpret_cast<const bf16x8*>(ehb + cl * 128 + (g16 ^ swc));
      bf16x8 bh1 = *reinterpret_cast<const bf16x8*>(ehb + cl * 128 + ((64 + g16) ^ swc));
      bf16x8 bl0 = *reinterpret_cast<const bf16x8*>(elb + cl * 128 + (g16 ^ swc));
      bf16x8 bl1 = *reinterpret_cast<const bf16x8*>(elb + cl * 128 + ((64 + g16) ^ swc));
      float esq_v = esq_s[cl];
      float fcode = (float)(chunk * 128 + cl);

      f32x4 acc0 = {0.f, 0.f, 0.f, 0.f};
      f32x4 acc1 = {0.f, 0.f, 0.f, 0.f};
      acc0 = __builtin_amdgcn_mfma_f32_16x16x32_bf16(a0h0, bh0, acc0, 0, 0, 0);
      acc1 = __builtin_amdgcn_mfma_f32_16x16x32_bf16(a1h0, bh0, acc1, 0, 0, 0);
      acc0 = __builtin_amdgcn_mfma_f32_16x16x32_bf16(a0h1, bh1, acc0, 0, 0, 0);
      acc1 = __builtin_amdgcn_mfma_f32_16x16x32_bf16(a1h1, bh1, acc1, 0, 0, 0);
      acc0 = __builtin_amdgcn_mfma_f32_16x16x32_bf16(a0h0, bl0, acc0, 0, 0, 0);
      acc1 = __builtin_amdgcn_mfma_f32_16x16x32_bf16(a1h0, bl0, acc1, 0, 0, 0);
      acc0 = __builtin_amdgcn_mfma_f32_16x16x32_bf16(a0h1, bl1, acc0, 0, 0, 0);
      acc1 = __builtin_amdgcn_mfma_f32_16x16x32_bf16(a1h1, bl1, acc1, 0, 0, 0);
      acc0 = __builtin_amdgcn_mfma_f32_16x16x32_bf16(a0l0, bh0, acc0, 0, 0, 0);
      acc1 = __builtin_amdgcn_mfma_f32_16x16x32_bf16(a1l0, bh0, acc1, 0, 0, 0);
      acc0 = __builtin_amdgcn_mfma_f32_16x16x32_bf16(a0l1, bh1, acc0, 0, 0, 0);
      acc1 = __builtin_amdgcn_mfma_f32_16x16x32_bf16(a1l1, bh1, acc1, 0, 0, 0);

#pragma unroll
      for (int j = 0; j < 4; ++j) {
        float s = 0.5f * esq_v - acc0[j];
        bool lt1 = s < s1a[0][j], lt2 = s < s2a[0][j], lt3 = s < s3a[0][j];
        s3a[0][j] = lt2 ? s2a[0][j] : (lt3 ? s : s3a[0][j]);
        s2a[0][j] = lt1 ? s1a[0][j] : (lt2 ? s : s2a[0][j]);
        i2a[0][j] = lt1 ? i1a[0][j] : (lt2 ? fcode : i2a[0][j]);
        s1a[0][j] = lt1 ? s : s1a[0][j];
        i1a[0][j] = lt1 ? fcode : i1a[0][j];
      }
#pragma unroll
      for (int j = 0; j < 4; ++j) {
        float s = 0.5f * esq_v - acc1[j];
        bool lt1 = s < s1a[1][j], lt2 = s < s2a[1][j], lt3 = s < s3a[1][j];
        s3a[1][j] = lt2 ? s2a[1][j] : (lt3 ? s : s3a[1][j]);
        s2a[1][j] = lt1 ? s1a[1][j] : (lt2 ? s : s2a[1][j]);
        i2a[1][j] = lt1 ? i1a[1][j] : (lt2 ? fcode : i2a[1][j]);
        s1a[1][j] = lt1 ? s : s1a[1][j];
        i1a[1][j] = lt1 ? fcode : i1a[1][j];
      }
    }
  }

  // ---- merge across the 16 lanes holding each point; write top-3 ----
  const int g = lane >> 4;
  float* ps1 = part;
  float* pi1 = part + N_PTS;
  float* ps2 = part + 2 * N_PTS;
  float* pi2 = part + 3 * N_PTS;
  float* ps3 = part + 4 * N_PTS;
#pragma unroll
  for (int rt = 0; rt < 2; ++rt)
#pragma unroll
    for (int j = 0; j < 4; ++j) {
      float v1 = s1a[rt][j], w1i = i1a[rt][j];
      float v2 = s2a[rt][j], w2i = i2a[rt][j];
      float v3 = s3a[rt][j];
      merge3(v1, w1i, v2, w2i, v3, 1);
      merge3(v1, w1i, v2, w2i, v3, 2);
      merge3(v1, w1i, v2, w2i, v3, 4);
      merge3(v1, w1i, v2, w2i, v3, 8);
      if ((lane & 15) == j) {
        int n = bb + wv * 32 + rt * 16 + g * 4 + j;
        ps1[n] = v1; pi1[n] = w1i; ps2[n] = v2; pi2[n] = w2i; ps3[n] = v3;
      }
    }
}

// ---------------- K2: finalize, tie-resolve, gather/eq/loss, zt ----------------
__global__ __launch_bounds__(256) void k_combine(
    const float* __restrict__ Z, const float* __restrict__ E,
    const float* __restrict__ part,
    float* __restrict__ eq_out, float* __restrict__ idx_out,
    float* __restrict__ counts, float* __restrict__ loss_acc,
    float* __restrict__ zt) {
  __shared__ float lred[4];
  const int n = blockIdx.x * 256 + threadIdx.x;
  const int zbase = (n >> 12) * BSTRIDE + (n & 4095);

  float zr[64];
#pragma unroll
  for (int d = 0; d < 64; ++d) zr[d] = Z[zbase + d * HW];
  float zsq = 0.f;
#pragma unroll
  for (int d = 0; d < 64; ++d) zsq = fmaf(zr[d], zr[d], zsq);

  float w1 = zsq + 2.f * part[n];
  int i1g = (int)part[N_PTS + n];
  float w2 = zsq + 2.f * part[2 * N_PTS + n];
  int i2g = (int)part[3 * N_PTS + n];
  float w3 = zsq + 2.f * part[4 * N_PTS + n];

  if (zt) {
    float4* zt4 = reinterpret_cast<float4*>(zt + (size_t)n * 64);
#pragma unroll
    for (int j = 0; j < 16; ++j)
      zt4[j] = make_float4(zr[4 * j + 0], zr[4 * j + 1], zr[4 * j + 2], zr[4 * j + 3]);
  }

  int bi = i1g;
  if (w3 - w1 < MX_FULL) {
    double b = 1e300; int bb = 0;
    for (int c = 0; c < K_CODES; ++c) {
      const float* ep = E + c * D_DIM;
      double s = 0.0;
      for (int d = 0; d < 64; ++d) {
        double v = (double)zr[d] - (double)ep[d];
        s += v * v;
      }
      if (s < b) { b = s; bb = c; }
    }
    bi = bb;
  } else if (w2 - w1 < MX_RESCORE) {
    const float* ea = E + i1g * D_DIM;
    const float* eb = E + i2g * D_DIM;
    double da = 0.0, db = 0.0;
#pragma unroll
    for (int d = 0; d < 64; ++d) {
      double va = (double)zr[d] - (double)ea[d]; da += va * va;
      double vb = (double)zr[d] - (double)eb[d]; db += vb * vb;
    }
    if (db < da || (db == da && i2g < i1g)) bi = i2g;
  }

  idx_out[n] = (float)bi;
  atomicAdd(&counts[bi], 1.0f);

  const float4* er = reinterpret_cast<const float4*>(E + bi * D_DIM);
  float lsum = 0.f;
#pragma unroll
  for (int j = 0; j < 16; ++j) {
    float4 ev = er[j];
    int d = 4 * j;
    eq_out[zbase + (d + 0) * HW] = ev.x;
    eq_out[zbase + (d + 1) * HW] = ev.y;
    eq_out[zbase + (d + 2) * HW] = ev.z;
    eq_out[zbase + (d + 3) * HW] = ev.w;
    float f0 = ev.x - zr[d + 0], f1 = ev.y - zr[d + 1];
    float f2 = ev.z - zr[d + 2], f3 = ev.w - zr[d + 3];
    lsum = fmaf(f0, f0, lsum); lsum = fmaf(f1, f1, lsum);
    lsum = fmaf(f2, f2, lsum); lsum = fmaf(f3, f3, lsum);
  }
#pragma unroll
  for (int off = 32; off >= 1; off >>= 1) lsum += __shfl_xor(lsum, off, 64);
  int lane = threadIdx.x & 63, wid = threadIdx.x >> 6;
  if (lane == 0) lred[wid] = lsum;
  __syncthreads();
  if (threadIdx.x == 0)
    atomicAdd(loss_acc, lred[0] + lred[1] + lred[2] + lred[3]);
}

// ---------------- fallback: single-pass fp32 assign (if ws too small) ----------------
__global__ __launch_bounds__(256) void k_solo(
    const float* __restrict__ Z, const float* __restrict__ E,
    const float* __restrict__ esq,
    float* __restrict__ eq_out, float* __restrict__ idx_out,
    float* __restrict__ counts, float* __restrict__ loss_acc) {
  __shared__ float sE[CHUNK * D_DIM];
  __shared__ float sQ[CHUNK];
  int n = blockIdx.x * 256 + threadIdx.x;
  int zbase = (n >> 12) * BSTRIDE + (n & 4095);

  float zr[64];
#pragma unroll
  for (int d = 0; d < 64; ++d) zr[d] = Z[zbase + d * HW];
  float zsq = 0.f;
#pragma unroll
  for (int d = 0; d < 64; ++d) zsq = fmaf(zr[d], zr[d], zsq);

  float b1 = 3.4e38f, b2 = 3.4e38f, b3 = 3.4e38f;
  int i1 = 0, i2 = 0;
  for (int ch = 0; ch < K_CODES / CHUNK; ++ch) {
    __syncthreads();
    const float4* src = reinterpret_cast<const float4*>(E + ch * CHUNK * D_DIM);
    float4* dst = reinterpret_cast<float4*>(sE);
#pragma unroll
    for (int j = 0; j < 8; ++j) dst[threadIdx.x + 256 * j] = src[threadIdx.x + 256 * j];
    if (threadIdx.x < CHUNK) sQ[threadIdx.x] = esq[ch * CHUNK + threadIdx.x];
    __syncthreads();
    for (int c = 0; c < CHUNK; ++c) {
      const float4* ep = reinterpret_cast<const float4*>(sE + c * D_DIM);
      float d0 = 0.f, d1 = 0.f, d2 = 0.f, d3 = 0.f;
#pragma unroll
      for (int j = 0; j < 16; ++j) {
        float4 v = ep[j];
        d0 = fmaf(zr[4 * j + 0], v.x, d0);
        d1 = fmaf(zr[4 * j + 1], v.y, d1);
        d2 = fmaf(zr[4 * j + 2], v.z, d2);
        d3 = fmaf(zr[4 * j + 3], v.w, d3);
      }
      float dist = zsq + sQ[c] - 2.f * ((d0 + d1) + (d2 + d3));
      int cg = ch * CHUNK + c;
      bool lt1 = dist < b1, lt2 = dist < b2, lt3 = dist < b3;
      b3 = lt2 ? b2 : (lt3 ? dist : b3);
      b2 = lt1 ? b1 : (lt2 ? dist : b2);
      i2 = lt1 ? i1 : (lt2 ? cg : i2);
      b1 = lt1 ? dist : b1;
      i1 = lt1 ? cg : i1;
    }
  }
  int bi = i1;
  if (b3 - b1 < M_FULL) {
    double b = 1e300; int bb = 0;
    for (int c = 0; c < K_CODES; ++c) {
      const float* ep = E + c * D_DIM;
      double s = 0.0;
      for (int d = 0; d < 64; ++d) { double v = (double)zr[d] - (double)ep[d]; s += v * v; }
      if (s < b) { b = s; bb = c; }
    }
    bi = bb;
  } else if (b2 - b1 < M_RESCORE) {
    const float* ea = E + i1 * D_DIM;
    const float* eb = E + i2 * D_DIM;
    double da = 0.0, db = 0.0;
#pragma unroll
    for (int d = 0; d < 64; ++d) {
      double va = (double)zr[d] - (double)ea[d]; da += va * va;
      double vb = (double)zr[d] - (double)eb[d]; db += vb * vb;
    }
    if (db < da || (db == da && i2 < i1)) bi = i2;
  }

  idx_out[n] = (float)bi;
  atomicAdd(&counts[bi], 1.0f);
  const float4* er = reinterpret_cast<const float4*>(E + bi * D_DIM);
  float lsum = 0.f;
#pragma unroll
  for (int j = 0; j < 16; ++j) {
    float4 ev = er[j];
    int d = 4 * j;
    eq_out[zbase + (d + 0) * HW] = ev.x;
    eq_out[zbase + (d + 1) * HW] = ev.y;
    eq_out[zbase + (d + 2) * HW] = ev.z;
    eq_out[zbase + (d + 3) * HW] = ev.w;
    float f0 = ev.x - zr[d + 0], f1 = ev.y - zr[d + 1];
    float f2 = ev.z - zr[d + 2], f3 = ev.w - zr[d + 3];
    lsum = fmaf(f0, f0, lsum); lsum = fmaf(f1, f1, lsum);
    lsum = fmaf(f2, f2, lsum); lsum = fmaf(f3, f3, lsum);
  }
#pragma unroll
  for (int off = 32; off >= 1; off >>= 1) lsum += __shfl_xor(lsum, off, 64);
  if ((threadIdx.x & 63) == 0) atomicAdd(loss_acc, lsum);
}

// ---------------- K3: stats, smoothing scalars, threefry ----------------
__global__ __launch_bounds__(1024) void k_stats(
    const float* __restrict__ counts, const float* __restrict__ cluster_size,
    float* __restrict__ out, float* __restrict__ ws,
    unsigned* __restrict__ rnd, const float* __restrict__ loss_acc) {
  __shared__ float red[16][4];
  int c = threadIdx.x;
  float cnt = counts[c];
  float csb = cluster_size[c] * 0.99f + cnt * 0.01f;
  out[OFF_CSB + c] = csb;

  float v_n = csb;
  float v_s = csb + 1e-5f;
  float p = cnt * (1.0f / 65536.0f);
  float v_p = p * logf(p + 1e-10f);
  float v_u = cnt > 0.f ? 1.f : 0.f;
#pragma unroll
  for (int off = 32; off >= 1; off >>= 1) {
    v_n += __shfl_xor(v_n, off, 64);
    v_s += __shfl_xor(v_s, off, 64);
    v_p += __shfl_xor(v_p, off, 64);
    v_u += __shfl_xor(v_u, off, 64);
  }
  int lane = threadIdx.x & 63, wid = threadIdx.x >> 6;
  if (lane == 0) { red[wid][0] = v_n; red[wid][1] = v_s; red[wid][2] = v_p; red[wid][3] = v_u; }
  __syncthreads();
  if (threadIdx.x == 0) {
    float nsum = 0.f, ssum = 0.f, psum = 0.f, usum = 0.f;
    for (int w = 0; w < 16; ++w) {
      nsum += red[w][0]; ssum += red[w][1]; psum += red[w][2]; usum += red[w][3];
    }
    ws[WS_NVAL] = nsum;
    ws[WS_SCS]  = ssum;
    out[OFF_STATS + 0] = expf(-psum);
    out[OFF_STATS + 1] = usum;
    out[OFF_LOSS] = 1.25f * loss_acc[0] * (1.0f / 4194304.0f);
  }
  rnd[c] = tf_rand_bits(c) & 0xFFFFu;
}

// ---------------- K4 fast: 4-wave ballot scan over z_t ----------------
__global__ __launch_bounds__(256) void k_update2(
    const float* __restrict__ zt, const float* __restrict__ embed_avg,
    const float* __restrict__ ws, const unsigned* __restrict__ rnd,
    const float* __restrict__ idxf, float* __restrict__ out) {
  __shared__ float sm[4][64];
  const int c = blockIdx.x;
  const int d = threadIdx.x & 63, w = threadIdx.x >> 6;
  const float cf = (float)c;
  float es = 0.f;
  const float4* i4 = reinterpret_cast<const float4*>(idxf);
  const int it0 = w * 64, it1 = it0 + 64;
  float4 cur = i4[it0 * 64 + d];
  for (int it = it0; it < it1; ++it) {
    float4 nxt = cur;
    if (it + 1 < it1) nxt = i4[(it + 1) * 64 + d];
    unsigned long long m0 = __ballot(cur.x == cf);
    unsigned long long m1 = __ballot(cur.y == cf);
    unsigned long long m2 = __ballot(cur.z == cf);
    unsigned long long m3 = __ballot(cur.w == cf);
    while (m0) { int b = __ffsll(m0) - 1; m0 &= m0 - 1;
      size_t p = (size_t)(it * 256 + b * 4 + 0); es += zt[p * 64 + d]; }
    while (m1) { int b = __ffsll(m1) - 1; m1 &= m1 - 1;
      size_t p = (size_t)(it * 256 + b * 4 + 1); es += zt[p * 64 + d]; }
    while (m2) { int b = __ffsll(m2) - 1; m2 &= m2 - 1;
      size_t p = (size_t)(it * 256 + b * 4 + 2); es += zt[p * 64 + d]; }
    while (m3) { int b = __ffsll(m3) - 1; m3 &= m3 - 1;
      size_t p = (size_t)(it * 256 + b * 4 + 3); es += zt[p * 64 + d]; }
    cur = nxt;
  }
  sm[w][d] = es;
  __syncthreads();
  if (w == 0) {
    es = ((sm[0][d] + sm[1][d]) + sm[2][d]) + sm[3][d];
    float csb = out[OFF_CSB + c];
    float nval = ws[WS_NVAL], scs = ws[WS_SCS];
    float cs = (csb + 1e-5f) / fmaxf(scs, 1e-8f) * nval;
    bool dead = cs < 1.0f;
    float csf = dead ? 1.0f : cs;
    float ea_ema = embed_avg[c * D_DIM + d] * 0.99f + es * 0.01f;
    int r = (int)rnd[c];
    float zv = zt[(size_t)r * 64 + d];
    float ea = dead ? zv : ea_ema;
    out[OFF_EAB + c * D_DIM + d] = ea;
    out[OFF_EMB + c * D_DIM + d] = ea / csf;
  }
}

// ---------------- K4 slow fallback: strided Z gather ----------------
__global__ __launch_bounds__(64) void k_update_slow(
    const float* __restrict__ Z, const float* __restrict__ embed_avg,
    const float* __restrict__ ws, const unsigned* __restrict__ rnd,
    const float* __restrict__ idxf, float* __restrict__ out) {
  const int c = blockIdx.x, d = threadIdx.x;
  const float cf = (float)c;
  float es = 0.f;
  const float4* i4 = reinterpret_cast<const float4*>(idxf);
  float4 cur = i4[d];
  for (int it = 0; it < 256; ++it) {
    float4 nxt = cur;
    if (it < 255) nxt = i4[(it + 1) * 64 + d];
    unsigned long long m0 = __ballot(cur.x == cf);
    unsigned long long m1 = __ballot(cur.y == cf);
    unsigned long long m2 = __ballot(cur.z == cf);
    unsigned long long m3 = __ballot(cur.w == cf);
    while (m0) { int b = __ffsll(m0) - 1; m0 &= m0 - 1;
      int p = it * 256 + b * 4 + 0; es += Z[(p >> 12) * BSTRIDE + d * HW + (p & 4095)]; }
    while (m1) { int b = __ffsll(m1) - 1; m1 &= m1 - 1;
      int p = it * 256 + b * 4 + 1; es += Z[(p >> 12) * BSTRIDE + d * HW + (p & 4095)]; }
    while (m2) { int b = __ffsll(m2) - 1; m2 &= m2 - 1;
      int p = it * 256 + b * 4 + 2; es += Z[(p >> 12) * BSTRIDE + d * HW + (p & 4095)]; }
    while (m3) { int b = __ffsll(m3) - 1; m3 &= m3 - 1;
      int p = it * 256 + b * 4 + 3; es += Z[(p >> 12) * BSTRIDE + d * HW + (p & 4095)]; }
    cur = nxt;
  }
  float csb = out[OFF_CSB + c];
  float nval = ws[WS_NVAL], scs = ws[WS_SCS];
  float cs = (csb + 1e-5f) / fmaxf(scs, 1e-8f) * nval;
  bool dead = cs < 1.0f;
  float csf = dead ? 1.0f : cs;
  float ea_ema = embed_avg[c * D_DIM + d] * 0.99f + es * 0.01f;
  int r = (int)rnd[c];
  float zv = Z[(r >> 12) * BSTRIDE + d * HW + (r & 4095)];
  float ea = dead ? zv : ea_ema;
  out[OFF_EAB + c * D_DIM + d] = ea;
  out[OFF_EMB + c * D_DIM + d] = ea / csf;
}

extern "C" void kernel_launch(void* const* d_in, const int* in_sizes, int n_in,
                              void* d_out, int out_size, void* d_ws, size_t ws_size,
                              hipStream_t stream) {
  const float* Z  = (const float*)d_in[0];
  const float* E  = (const float*)d_in[1];
  const float* CS = (const float*)d_in[2];
  const float* EA = (const float*)d_in[3];
  float* out = (float*)d_out;
  float* ws  = (float*)d_ws;
  unsigned* rnd = (unsigned*)(ws + WS_RAND);

  const size_t need = (size_t)(WS_ZT + (size_t)N_PTS * D_DIM + 16) * sizeof(float);
  const bool big = ws_size >= need;

  hipMemsetAsync(ws, 0, 1028 * sizeof(float), stream);
  k_esq<<<4, 256, 0, stream>>>(E, ws + WS_ESQ);
  if (big) {
    unsigned short* ehi = (unsigned short*)(ws + WS_EHI);
    unsigned short* elo = (unsigned short*)(ws + WS_ELO);
    float* zt = ws + WS_ZT;
    k_cvt<<<256, 256, 0, stream>>>(E, ehi, elo);
    k_assign_mfma<<<N_PTS / 128, 256, 0, stream>>>(Z, ehi, elo, ws + WS_ESQ, ws + WS_PART);
    k_combine<<<N_PTS / 256, 256, 0, stream>>>(Z, E, ws + WS_PART,
                                               out + OFF_EQ, out + OFF_IDX,
                                               ws + WS_CNT, ws + WS_LOSS, zt);
    k_stats<<<1, 1024, 0, stream>>>(ws + WS_CNT, CS, out, ws, rnd, ws + WS_LOSS);
    k_update2<<<K_CODES, 256, 0, stream>>>(zt, EA, ws, rnd, out + OFF_IDX, out);
  } else {
    k_solo<<<N_PTS / 256, 256, 0, stream>>>(Z, E, ws + WS_ESQ,
                                            out + OFF_EQ, out + OFF_IDX,
                                            ws + WS_CNT, ws + WS_LOSS);
    k_stats<<<1, 1024, 0, stream>>>(ws + WS_CNT, CS, out, ws, rnd, ws + WS_LOSS);
    k_update_slow<<<K_CODES, 64, 0, stream>>>(Z, EA, ws, rnd, out + OFF_IDX, out);
  }
}